// Round 16
// baseline (1910.608 us; speedup 1.0000x reference)
//
#include <hip/hip_runtime.h>
#include <hip/hip_bf16.h>

#define DFEAT 256

typedef __bf16 bf16x8 __attribute__((ext_vector_type(8)));
typedef float  f32x4  __attribute__((ext_vector_type(4)));

// ---------------------------------------------------------------------------
// CSR build: histogram -> hierarchical scan (cursor + bucket bases in scan_add)
// ---------------------------------------------------------------------------
__global__ void hist2_kernel(const int* __restrict__ dA, int nA, int* __restrict__ PA,
                             const int* __restrict__ dB, int nB, int* __restrict__ PB) {
    int half = gridDim.x >> 1;
    if (blockIdx.x < half) {
        for (int e = blockIdx.x * blockDim.x + threadIdx.x; e < nA; e += half * blockDim.x)
            atomicAdd(&PA[dA[e] + 1], 1);
    } else {
        for (int e = (blockIdx.x - half) * blockDim.x + threadIdx.x; e < nB; e += half * blockDim.x)
            atomicAdd(&PB[dB[e] + 1], 1);
    }
}

__global__ __launch_bounds__(256) void scan_block2(
    int* __restrict__ am, int nm, int* __restrict__ bsm,
    int* __restrict__ au, int nu, int* __restrict__ bsu, int nbM)
{
    __shared__ int wsum[4];
    int* a; int n; int* bsum; int bid;
    if ((int)blockIdx.x < nbM) { a = am; n = nm; bsum = bsm; bid = blockIdx.x; }
    else                       { a = au; n = nu; bsum = bsu; bid = blockIdx.x - nbM; }
    const int tid = threadIdx.x;
    const int lane = tid & 63, wv = tid >> 6;
    const int idx = bid * 2048 + tid * 8;
    int v[8];
    #pragma unroll
    for (int i = 0; i < 8; ++i) v[i] = (idx + i < n) ? a[idx + i] : 0;
    #pragma unroll
    for (int i = 1; i < 8; ++i) v[i] += v[i - 1];
    int tsum = v[7];
    int sc = tsum;
    #pragma unroll
    for (int off = 1; off < 64; off <<= 1) {
        int t = __shfl_up(sc, off);
        if (lane >= off) sc += t;
    }
    if (lane == 63) wsum[wv] = sc;
    __syncthreads();
    int wadd = 0;
    for (int w2 = 0; w2 < wv; ++w2) wadd += wsum[w2];
    int texcl = sc - tsum + wadd;
    #pragma unroll
    for (int i = 0; i < 8; ++i)
        if (idx + i < n) a[idx + i] = v[i] + texcl;
    if (tid == 255) bsum[bid] = sc + wadd;
}

__global__ void scan_sums2(int* __restrict__ bsm, int nbM, int* __restrict__ bsu, int nbU) {
    int wv = threadIdx.x >> 6;
    int lane = threadIdx.x & 63;
    int* bs = wv ? bsu : bsm;
    int nb  = wv ? nbU : nbM;
    int v = (lane < nb) ? bs[lane] : 0;
    #pragma unroll
    for (int off = 1; off < 64; off <<= 1) {
        int t = __shfl_up(v, off);
        if (lane >= off) v += t;
    }
    if (lane < nb) bs[lane] = v;
}

// adds block prefixes; writes cursor copy AND per-bucket append bases
// (bcur[b] = rowptr[b << shift])
__global__ __launch_bounds__(256) void scan_add2(
    int* __restrict__ am, int nm, const int* __restrict__ bsm, int* __restrict__ curM,
    int* __restrict__ bcM, int shM,
    int* __restrict__ au, int nu, const int* __restrict__ bsu, int* __restrict__ curU,
    int* __restrict__ bcU, int shU, int nbM)
{
    int* a; int n; const int* bsum; int* cur; int* bc; int sh; int bid;
    if ((int)blockIdx.x < nbM) { a = am; n = nm; bsum = bsm; cur = curM; bc = bcM; sh = shM; bid = blockIdx.x; }
    else                       { a = au; n = nu; bsum = bsu; cur = curU; bc = bcU; sh = shU; bid = blockIdx.x - nbM; }
    int add = (bid == 0) ? 0 : bsum[bid - 1];
    int idx = bid * 2048 + threadIdx.x * 8;
    int mask = (1 << sh) - 1;
    #pragma unroll
    for (int i = 0; i < 8; ++i) {
        int d = idx + i;
        if (d < n) {
            int v = a[d] + add;
            if (bid > 0) a[d] = v;
            if (d < n - 1) {
                cur[d] = v;
                if ((d & mask) == 0) bc[d >> sh] = v;
            }
        }
    }
}

// ---------------------------------------------------------------------------
// Mega-prep: [0,4096) pass-1 bucket append (int2 temp records) |
// [4096,6144) f32->bf16 | [6144,8192) packed weight transpose.
// Pass 1: bucket b (= d >> shift) owned by XCD b&7; appends via per-bucket
// cursor are DENSE -> L2 lines fill before eviction (~1x writeback).
// ---------------------------------------------------------------------------
struct PrepArgs {
    const int* dstA; const int* srcA; const float* wA; int nA;
    int* bcA; int2* tmpA; int shA;
    const int* dstB; const int* srcB; const float* wB; int nB;
    int* bcB; int2* tmpB; int shB;
    const float* xu; __bf16* xu_bf; int n8u;
    const float* xm; __bf16* xm_bf; int n8m;
    const float* Wl[4]; const float* Wr[4]; __bf16* wout[4];
};

__global__ __launch_bounds__(256) void mega_prep(PrepArgs p) {
    const int b = blockIdx.x;
    const int tid = threadIdx.x;
    if (b < 4096) {
        const int* dst; const int* src; const float* w; int n; int* bc; int2* tmp; int sh;
        int within;
        if (b < 2048) { dst = p.dstA; src = p.srcA; w = p.wA; n = p.nA; bc = p.bcA; tmp = p.tmpA; sh = p.shA; within = b; }
        else          { dst = p.dstB; src = p.srcB; w = p.wB; n = p.nB; bc = p.bcB; tmp = p.tmpB; sh = p.shB; within = b - 2048; }
        const int r  = within & 7;          // bucket-group == XCD (blockIdx%8)
        const int lb = within >> 3;         // 0..255 within group
        for (int e = lb * 256 + tid; e < n; e += 256 * 256) {
            int d = dst[e];                 // coalesced; L3-hot after pass 1
            int bk = d >> sh;
            if ((bk & 7) == r) {
                int pos = atomicAdd(&bc[bk], 1);
                unsigned int wq = (unsigned int)fminf(rintf(w[e] * 32768.0f), 32767.0f);
                tmp[pos] = make_int2(d, (int)(((unsigned int)src[e] << 15) | wq));
            }
        }
    } else if (b < 6144) {
        int total = p.n8u + p.n8m;
        for (int i = (b - 4096) * 256 + tid; i < total; i += 2048 * 256) {
            const float* in; __bf16* out; int j;
            if (i < p.n8u) { in = p.xu; out = p.xu_bf; j = i; }
            else           { in = p.xm; out = p.xm_bf; j = i - p.n8u; }
            float4 x = *reinterpret_cast<const float4*>(in + (size_t)j * 8);
            float4 y = *reinterpret_cast<const float4*>(in + (size_t)j * 8 + 4);
            bf16x8 v;
            v[0] = (__bf16)x.x; v[1] = (__bf16)x.y; v[2] = (__bf16)x.z; v[3] = (__bf16)x.w;
            v[4] = (__bf16)y.x; v[5] = (__bf16)y.y; v[6] = (__bf16)y.z; v[7] = (__bf16)y.w;
            *reinterpret_cast<bf16x8*>(out + (size_t)j * 8) = v;
        }
    } else {
        // packed fragment-major weights: frag f = ncg*16+kc; lane l bytes f*1024+l*16
        int t = (b - 6144) * 256 + tid;          // 0 .. 524287
        int set = t >> 17;
        int e2  = t & 131071;
        int f = e2 >> 9;
        int e = e2 & 511;
        int l = e >> 3;
        int j = e & 7;
        int ncg = f >> 4;
        int kc  = f & 15;
        int col = ncg * 16 + (l & 15);
        int k   = kc * 32 + (l >> 4) * 8 + j;
        float v = (k < 256) ? p.Wl[set][(size_t)k * 256 + col]
                            : p.Wr[set][(size_t)(k - 256) * 256 + col];
        p.wout[set][e2] = (__bf16)v;
    }
}

// ---------------------------------------------------------------------------
// Pass 2: per-bucket scatter temp -> final dst-sorted records. Bucket final
// region is ~10-16 KB (L2-resident) -> ~1x writeback. One block per bucket.
// ---------------------------------------------------------------------------
__global__ __launch_bounds__(256) void scatter2(
    const int* __restrict__ rpM, const int2* __restrict__ tmpM, int* __restrict__ curM,
    unsigned int* __restrict__ recM, int ndM, int shM, int nbkM,
    const int* __restrict__ rpU, const int2* __restrict__ tmpU, int* __restrict__ curU,
    unsigned int* __restrict__ recU, int ndU, int shU)
{
    const int* rp; const int2* tmp; int* cur; unsigned int* rec; int nd; int sh; int bk;
    if ((int)blockIdx.x < nbkM) { rp = rpM; tmp = tmpM; cur = curM; rec = recM; nd = ndM; sh = shM; bk = blockIdx.x; }
    else                        { rp = rpU; tmp = tmpU; cur = curU; rec = recU; nd = ndU; sh = shU; bk = blockIdx.x - nbkM; }
    int dlo = bk << sh;
    int dhi = ((bk + 1) << sh); if (dhi > nd) dhi = nd;
    int base = rp[dlo];
    int endb = rp[dhi];
    for (int j = base + threadIdx.x; j < endb; j += 256) {
        int2 t = tmp[j];
        int pos = atomicAdd(&cur[t.x], 1);
        rec[pos] = (unsigned int)t.y;
    }
}

// ---------------------------------------------------------------------------
// Dual aggregation (movie side blocks [0,nbA), user side rest): one wave per
// dst row; 2 edges per wave-step (32 lanes x 16B), 16 edges in flight;
// cross-half combine via shfl_xor(32). Records are 4B packed (src<<15 | wq).
// ---------------------------------------------------------------------------
__global__ __launch_bounds__(256) void agg_dual(
    const __bf16* __restrict__ xA, const unsigned int* __restrict__ recA,
    const int* __restrict__ rpA, __bf16* __restrict__ meanA, int ndA, int nbA,
    const __bf16* __restrict__ xB, const unsigned int* __restrict__ recB,
    const int* __restrict__ rpB, __bf16* __restrict__ meanB, int ndB)
{
    const __bf16* xsrc; const unsigned int* rec; const int* rowptr; __bf16* mean; int ndst; int lb;
    if ((int)blockIdx.x < nbA) { xsrc = xA; rec = recA; rowptr = rpA; mean = meanA; ndst = ndA; lb = blockIdx.x; }
    else                       { xsrc = xB; rec = recB; rowptr = rpB; mean = meanB; ndst = ndB; lb = blockIdx.x - nbA; }
    int wid  = lb * 4 + (threadIdx.x >> 6);
    int lane = threadIdx.x & 63;
    if (wid >= ndst) return;
    int beg = rowptr[wid], end = rowptr[wid + 1];
    const int half = lane >> 5, hl = lane & 31;
    const __bf16* xcol = xsrc + hl * 8;
    const float wscale = 1.0f / 32768.0f;
    float acc[8];
    #pragma unroll
    for (int i = 0; i < 8; ++i) acc[i] = 0.f;

    int j0 = beg;
    while (j0 < end) {
        int m = end - j0; if (m > 64) m = 64;
        unsigned int rl = (lane < m) ? rec[j0 + lane] : 0u;
        int t = 0;
        for (; t + 16 <= m; t += 16) {
            bf16x8 v[8]; float wt[8];
            #pragma unroll
            for (int u = 0; u < 8; ++u) {
                int tt = t + u * 2;
                unsigned int r0 = (unsigned int)__builtin_amdgcn_readlane((int)rl, tt);
                unsigned int r1 = (unsigned int)__builtin_amdgcn_readlane((int)rl, tt + 1);
                unsigned int rr = half ? r1 : r0;
                wt[u] = (float)(rr & 32767u) * wscale;
                v[u] = *reinterpret_cast<const bf16x8*>(xcol + (size_t)(rr >> 15) * DFEAT);
            }
            #pragma unroll
            for (int u = 0; u < 8; ++u)
                #pragma unroll
                for (int i = 0; i < 8; ++i) acc[i] += wt[u] * (float)v[u][i];
        }
        for (; t < m; t += 2) {
            unsigned int r0 = (unsigned int)__builtin_amdgcn_readlane((int)rl, t);
            unsigned int r1 = (unsigned int)__builtin_amdgcn_readlane((int)rl, (t + 1 < 64) ? t + 1 : 63);
            unsigned int rr = half ? r1 : r0;
            float wv2 = (float)(rr & 32767u) * wscale;
            if (half && t + 1 >= m) wv2 = 0.f;
            bf16x8 v = *reinterpret_cast<const bf16x8*>(xcol + (size_t)(rr >> 15) * DFEAT);
            #pragma unroll
            for (int i = 0; i < 8; ++i) acc[i] += wv2 * (float)v[i];
        }
        j0 += m;
    }

    #pragma unroll
    for (int i = 0; i < 8; ++i) acc[i] += __shfl_xor(acc[i], 32);
    float inv = (end > beg) ? 1.0f / (float)(end - beg) : 0.0f;
    if (half == 0) {
        bf16x8 o;
        #pragma unroll
        for (int i = 0; i < 8; ++i) o[i] = (__bf16)(acc[i] * inv);
        *reinterpret_cast<bf16x8*>(mean + (size_t)wid * DFEAT + hl * 8) = o;
    }
}

// ---------------------------------------------------------------------------
// Dual MFMA GEMM, 2-deep pipeline (R10 structure): out = epi(A@Wl + B@Wr + b)
// ---------------------------------------------------------------------------
struct GemmSide {
    const __bf16* A; const __bf16* B; const __bf16* W;
    const float* bias; const __bf16* resid; void* out; int n;
};

template<int EPI>
__global__ __launch_bounds__(256) void gemm_dual(GemmSide s0, GemmSide s1, int nb0) {
    __shared__ char sA[3][64 * 128];      // 3 x 8 KB

    const GemmSide& S = ((int)blockIdx.x < nb0) ? s0 : s1;
    const int lblk = ((int)blockIdx.x < nb0) ? blockIdx.x : blockIdx.x - nb0;
    const __bf16* __restrict__ Amat = S.A;
    const __bf16* __restrict__ Bmat = S.B;
    const char* Wb = reinterpret_cast<const char*>(S.W);
    const int n = S.n;

    const int tid  = threadIdx.x;
    const int lane = tid & 63;
    const int wv   = tid >> 6;
    const int lo   = lane & 15;
    const int hi   = lane >> 4;
    const int brow = lblk * 64;
    const int wcol = wv * 64;
    const int nm1  = n - 1;

    f32x4 acc[4][4];
    #pragma unroll
    for (int i = 0; i < 4; ++i)
        #pragma unroll
        for (int j = 0; j < 4; ++j) acc[i][j] = (f32x4){0.f, 0.f, 0.f, 0.f};

    auto stage = [&](int chunk, int buf) {
        const __bf16* mat = (chunk < 4) ? Amat : Bmat;
        const int kbyte = (chunk & 3) * 128;
        #pragma unroll
        for (int q = 0; q < 2; ++q) {
            int s = q * 256 + tid;
            int r = s >> 3, sub = s & 7;
            int grow = brow + r; if (grow > nm1) grow = nm1;
            int srcoff = (sub * 16) ^ ((r & 7) << 4);
            const char* g = reinterpret_cast<const char*>(mat) + (size_t)grow * 512 + kbyte + srcoff;
            __builtin_amdgcn_global_load_lds(
                (const __attribute__((address_space(1))) void*)g,
                (__attribute__((address_space(3))) void*)(sA[buf] + s * 16), 16, 0, 0);
        }
    };

    const int lb = lane * 16;
    bf16x8 bqA[2][4], bqB[2][4];
    auto loadB = [&](int chunk, bf16x8 (&dst)[2][4]) {
        #pragma unroll
        for (int ks = 0; ks < 2; ++ks)
            #pragma unroll
            for (int nn = 0; nn < 4; ++nn)
                dst[ks][nn] = *reinterpret_cast<const bf16x8*>(
                    Wb + (size_t)(((wv * 4 + nn) * 16 + chunk * 2 + ks) << 10) + lb);
    };

    stage(0, 0);
    stage(1, 1);
    loadB(0, bqA);

    #pragma unroll
    for (int c = 0; c < 8; ++c) {
        asm volatile("s_waitcnt vmcnt(10)" ::: "memory");
        __builtin_amdgcn_s_barrier();
        __builtin_amdgcn_sched_barrier(0);
        if (c < 6) stage(c + 2, (c + 2) % 3);
        const int cur = c % 3;
        auto compute = [&](bf16x8 (&bq)[2][4]) {
            #pragma unroll
            for (int ks = 0; ks < 2; ++ks) {
                const int kb = ks * 64 + hi * 16;
                #pragma unroll
                for (int mm = 0; mm < 4; ++mm) {
                    int r = mm * 16 + lo;
                    bf16x8 a = *reinterpret_cast<const bf16x8*>(
                        sA[cur] + r * 128 + (kb ^ ((r & 7) << 4)));
                    #pragma unroll
                    for (int nn = 0; nn < 4; ++nn)
                        acc[mm][nn] = __builtin_amdgcn_mfma_f32_16x16x32_bf16(
                            a, bq[ks][nn], acc[mm][nn], 0, 0, 0);
                }
            }
        };
        if ((c & 1) == 0) { if (c < 7) loadB(c + 1, bqB); compute(bqA); }
        else              { if (c < 7) loadB(c + 1, bqA); compute(bqB); }
    }

    #pragma unroll
    for (int mm = 0; mm < 4; ++mm) {
        #pragma unroll
        for (int nn = 0; nn < 4; ++nn) {
            int col = wcol + nn * 16 + lo;
            float bv2 = S.bias[col];
            #pragma unroll
            for (int r = 0; r < 4; ++r) {
                int grow = brow + mm * 16 + hi * 4 + r;
                if (grow >= n) continue;
                float v = acc[mm][nn][r] + bv2;
                if (EPI == 1) {
                    float rv = (float)S.resid[(size_t)grow * DFEAT + col];
                    ((__bf16*)S.out)[(size_t)grow * DFEAT + col] =
                        (__bf16)(rv + fmaxf(v, 0.f));
                } else {
                    ((float*)S.out)[(size_t)grow * DFEAT + col] = v;
                }
            }
        }
    }
}

// ---------------------------------------------------------------------------
extern "C" void kernel_launch(void* const* d_in, const int* in_sizes, int n_in,
                              void* d_out, int out_size, void* d_ws, size_t ws_size,
                              hipStream_t stream) {
    const float* x_user  = (const float*)d_in[0];
    const float* x_movie = (const float*)d_in[1];
    const int*   src_um  = (const int*)d_in[2];
    const int*   dst_um  = (const int*)d_in[3];
    const float* w_um    = (const float*)d_in[4];
    const int*   src_mu  = (const int*)d_in[5];
    const int*   dst_mu  = (const int*)d_in[6];
    const float* w_mu    = (const float*)d_in[7];
    const float* c1_um_Wl = (const float*)d_in[8];
    const float* c1_um_Wr = (const float*)d_in[9];
    const float* c1_um_b  = (const float*)d_in[10];
    const float* c1_mu_Wl = (const float*)d_in[11];
    const float* c1_mu_Wr = (const float*)d_in[12];
    const float* c1_mu_b  = (const float*)d_in[13];
    const float* c2_um_Wl = (const float*)d_in[14];
    const float* c2_um_Wr = (const float*)d_in[15];
    const float* c2_um_b  = (const float*)d_in[16];
    const float* c2_mu_Wl = (const float*)d_in[17];
    const float* c2_mu_Wr = (const float*)d_in[18];
    const float* c2_mu_b  = (const float*)d_in[19];

    const int NU = in_sizes[0] / DFEAT;
    const int NM = in_sizes[1] / DFEAT;
    const int E_um = in_sizes[2];
    const int E_mu = in_sizes[5];
    const int SH_M = 6;                    // movie bucket = 64 dsts
    const int SH_U = 8;                    // user bucket = 256 dsts
    const int nbkM = (NM + 63) >> 6;       // 313
    const int nbkU = (NU + 255) >> 8;      // 391

    char* p = (char*)d_ws;
    auto carve = [&](size_t bytes) { char* r = p; p += (bytes + 255) & ~(size_t)255; return r; };
    int* rowptr_m = (int*)carve((size_t)(NM + 1) * 4);
    int* rowptr_u = (int*)carve((size_t)(NU + 1) * 4);
    int* cursor_m = (int*)carve((size_t)NM * 4);
    int* cursor_u = (int*)carve((size_t)NU * 4);
    int* bsum_m   = (int*)carve(64 * 4);
    int* bsum_u   = (int*)carve(64 * 4);
    int* bcur_m   = (int*)carve((size_t)nbkM * 4);
    int* bcur_u   = (int*)carve((size_t)nbkU * 4);
    __bf16* xu_bf = (__bf16*)carve((size_t)NU * DFEAT * 2);
    __bf16* xm_bf = (__bf16*)carve((size_t)NM * DFEAT * 2);
    __bf16* ru_bf = (__bf16*)carve((size_t)NU * DFEAT * 2);
    __bf16* rm_bf = (__bf16*)carve((size_t)NM * DFEAT * 2);
    __bf16* wt_c1um = (__bf16*)carve(256 * 512 * 2);
    __bf16* wt_c1mu = (__bf16*)carve(256 * 512 * 2);
    __bf16* wt_c2um = (__bf16*)carve(256 * 512 * 2);
    __bf16* wt_c2mu = (__bf16*)carve(256 * 512 * 2);

    // records + temp in the dead tail of d_out (consumed before final writes)
    char* dtail = (char*)d_out + (size_t)(NU + NM) * DFEAT * 2;
    unsigned int* rec_m = (unsigned int*)(dtail);
    unsigned int* rec_u = (unsigned int*)(dtail + (size_t)E_um * 4);
    int2* tmp_m = (int2*)(dtail + (size_t)(E_um + E_mu) * 4);
    int2* tmp_u = (int2*)(dtail + (size_t)(E_um + E_mu) * 4 + (size_t)E_um * 8);

    __bf16* mean1_u = (__bf16*)d_out;
    __bf16* mean1_m = (__bf16*)d_out + (size_t)NU * DFEAT;
    float* out_user  = (float*)d_out;
    float* out_movie = (float*)d_out + (size_t)NU * DFEAT;

    // ---- CSR build ----
    size_t msz = ((((size_t)(NM + 1) * 4) + 255) & ~(size_t)255) + (size_t)(NU + 1) * 4;
    hipMemsetAsync(rowptr_m, 0, msz, stream);   // covers rowptr_m + rowptr_u
    hist2_kernel<<<4096, 256, 0, stream>>>(dst_um, E_um, rowptr_m, dst_mu, E_mu, rowptr_u);
    const int nbM = (NM + 1 + 2047) / 2048;
    const int nbU = (NU + 1 + 2047) / 2048;
    scan_block2<<<nbM + nbU, 256, 0, stream>>>(rowptr_m, NM + 1, bsum_m, rowptr_u, NU + 1, bsum_u, nbM);
    scan_sums2<<<1, 128, 0, stream>>>(bsum_m, nbM, bsum_u, nbU);
    scan_add2<<<nbM + nbU, 256, 0, stream>>>(rowptr_m, NM + 1, bsum_m, cursor_m, bcur_m, SH_M,
                                             rowptr_u, NU + 1, bsum_u, cursor_u, bcur_u, SH_U, nbM);

    // ---- mega prep: bucket append + bf16 features + packed weights ----
    PrepArgs pa;
    pa.dstA = dst_um; pa.srcA = src_um; pa.wA = w_um; pa.nA = E_um; pa.bcA = bcur_m; pa.tmpA = tmp_m; pa.shA = SH_M;
    pa.dstB = dst_mu; pa.srcB = src_mu; pa.wB = w_mu; pa.nB = E_mu; pa.bcB = bcur_u; pa.tmpB = tmp_u; pa.shB = SH_U;
    pa.xu = x_user;  pa.xu_bf = xu_bf; pa.n8u = NU * DFEAT / 8;
    pa.xm = x_movie; pa.xm_bf = xm_bf; pa.n8m = NM * DFEAT / 8;
    pa.Wl[0] = c1_um_Wl; pa.Wr[0] = c1_um_Wr; pa.wout[0] = wt_c1um;
    pa.Wl[1] = c1_mu_Wl; pa.Wr[1] = c1_mu_Wr; pa.wout[1] = wt_c1mu;
    pa.Wl[2] = c2_um_Wl; pa.Wr[2] = c2_um_Wr; pa.wout[2] = wt_c2um;
    pa.Wl[3] = c2_mu_Wl; pa.Wr[3] = c2_mu_Wr; pa.wout[3] = wt_c2mu;
    mega_prep<<<8192, 256, 0, stream>>>(pa);

    // ---- pass 2: bucket-local scatter to final dst-sorted records ----
    scatter2<<<nbkM + nbkU, 256, 0, stream>>>(rowptr_m, tmp_m, cursor_m, rec_m, NM, SH_M, nbkM,
                                              rowptr_u, tmp_u, cursor_u, rec_u, NU, SH_U);

    const int gaM = (NM + 3) / 4, gaU = (NU + 3) / 4;
    const int gbM = (NM + 63) / 64, gbU = (NU + 63) / 64;

    // ---- layer 1 ----
    agg_dual<<<gaM + gaU, 256, 0, stream>>>(xu_bf, rec_m, rowptr_m, mean1_m, NM, gaM,
                                            xm_bf, rec_u, rowptr_u, mean1_u, NU);
    GemmSide g1m = {mean1_m, xm_bf, wt_c1um, c1_um_b, xm_bf, rm_bf, NM};
    GemmSide g1u = {mean1_u, xu_bf, wt_c1mu, c1_mu_b, xu_bf, ru_bf, NU};
    gemm_dual<1><<<gbM + gbU, 256, 0, stream>>>(g1m, g1u, gbM);

    // ---- layer 2 (means reuse dead x_bf buffers) ----
    __bf16* mean2_m = xm_bf;
    __bf16* mean2_u = xu_bf;
    agg_dual<<<gaM + gaU, 256, 0, stream>>>(ru_bf, rec_m, rowptr_m, mean2_m, NM, gaM,
                                            rm_bf, rec_u, rowptr_u, mean2_u, NU);
    GemmSide g2m = {mean2_m, rm_bf, wt_c2um, c2_um_b, nullptr, out_movie, NM};
    GemmSide g2u = {mean2_u, ru_bf, wt_c2mu, c2_mu_b, nullptr, out_user, NU};
    gemm_dual<0><<<gbM + gbU, 256, 0, stream>>>(g2m, g2u, gbM);
}

// Round 17
// 618.758 us; speedup vs baseline: 3.0878x; 3.0878x over previous
//
#include <hip/hip_runtime.h>
#include <hip/hip_bf16.h>

#define DFEAT 256

typedef __bf16 bf16x8 __attribute__((ext_vector_type(8)));
typedef float  f32x4  __attribute__((ext_vector_type(4)));

// ---------------------------------------------------------------------------
// CSR build: histogram -> hierarchical scan (cursor written in scan_add)
// ---------------------------------------------------------------------------
__global__ void hist2_kernel(const int* __restrict__ dA, int nA, int* __restrict__ PA,
                             const int* __restrict__ dB, int nB, int* __restrict__ PB) {
    int half = gridDim.x >> 1;
    if (blockIdx.x < half) {
        for (int e = blockIdx.x * blockDim.x + threadIdx.x; e < nA; e += half * blockDim.x)
            atomicAdd(&PA[dA[e] + 1], 1);
    } else {
        for (int e = (blockIdx.x - half) * blockDim.x + threadIdx.x; e < nB; e += half * blockDim.x)
            atomicAdd(&PB[dB[e] + 1], 1);
    }
}

__global__ __launch_bounds__(256) void scan_block2(
    int* __restrict__ am, int nm, int* __restrict__ bsm,
    int* __restrict__ au, int nu, int* __restrict__ bsu, int nbM)
{
    __shared__ int wsum[4];
    int* a; int n; int* bsum; int bid;
    if ((int)blockIdx.x < nbM) { a = am; n = nm; bsum = bsm; bid = blockIdx.x; }
    else                       { a = au; n = nu; bsum = bsu; bid = blockIdx.x - nbM; }
    const int tid = threadIdx.x;
    const int lane = tid & 63, wv = tid >> 6;
    const int idx = bid * 2048 + tid * 8;
    int v[8];
    #pragma unroll
    for (int i = 0; i < 8; ++i) v[i] = (idx + i < n) ? a[idx + i] : 0;
    #pragma unroll
    for (int i = 1; i < 8; ++i) v[i] += v[i - 1];
    int tsum = v[7];
    int sc = tsum;
    #pragma unroll
    for (int off = 1; off < 64; off <<= 1) {
        int t = __shfl_up(sc, off);
        if (lane >= off) sc += t;
    }
    if (lane == 63) wsum[wv] = sc;
    __syncthreads();
    int wadd = 0;
    for (int w2 = 0; w2 < wv; ++w2) wadd += wsum[w2];
    int texcl = sc - tsum + wadd;
    #pragma unroll
    for (int i = 0; i < 8; ++i)
        if (idx + i < n) a[idx + i] = v[i] + texcl;
    if (tid == 255) bsum[bid] = sc + wadd;
}

__global__ void scan_sums2(int* __restrict__ bsm, int nbM, int* __restrict__ bsu, int nbU) {
    int wv = threadIdx.x >> 6;
    int lane = threadIdx.x & 63;
    int* bs = wv ? bsu : bsm;
    int nb  = wv ? nbU : nbM;
    int v = (lane < nb) ? bs[lane] : 0;
    #pragma unroll
    for (int off = 1; off < 64; off <<= 1) {
        int t = __shfl_up(v, off);
        if (lane >= off) v += t;
    }
    if (lane < nb) bs[lane] = v;
}

// adds block prefixes AND writes the cursor copy (cursor[d] = rowptr[d])
__global__ __launch_bounds__(256) void scan_add2(
    int* __restrict__ am, int nm, const int* __restrict__ bsm, int* __restrict__ curM,
    int* __restrict__ au, int nu, const int* __restrict__ bsu, int* __restrict__ curU, int nbM)
{
    int* a; int n; const int* bsum; int* cur; int bid;
    if ((int)blockIdx.x < nbM) { a = am; n = nm; bsum = bsm; cur = curM; bid = blockIdx.x; }
    else                       { a = au; n = nu; bsum = bsu; cur = curU; bid = blockIdx.x - nbM; }
    int add = (bid == 0) ? 0 : bsum[bid - 1];
    int idx = bid * 2048 + threadIdx.x * 8;
    #pragma unroll
    for (int i = 0; i < 8; ++i) {
        if (idx + i < n) {
            int v = a[idx + i] + add;
            if (bid > 0) a[idx + i] = v;
            if (idx + i < n - 1) cur[idx + i] = v;
        }
    }
}

// ---------------------------------------------------------------------------
// Mega-prep: [0,4096) XCD-partitioned edge fill (4B packed records) |
// [4096,6144) f32->bf16 | [6144,8192) packed weight transpose.
// Record = (src << 15) | wq, wq = round(w * 32768).
// Edge streams are read NON-TEMPORAL (nt) so they don't evict the
// partially-filled record lines from the XCD's L2 -> ~1 writeback/line.
// ---------------------------------------------------------------------------
struct PrepArgs {
    const int* dstA; const int* srcA; const float* wA; int nA; int ndA;
    int* curA; unsigned int* recA;
    const int* dstB; const int* srcB; const float* wB; int nB; int ndB;
    int* curB; unsigned int* recB;
    const float* xu; __bf16* xu_bf; int n8u;
    const float* xm; __bf16* xm_bf; int n8m;
    const float* Wl[4]; const float* Wr[4]; __bf16* wout[4];
};

__global__ __launch_bounds__(256) void mega_prep(PrepArgs p) {
    const int b = blockIdx.x;
    const int tid = threadIdx.x;
    if (b < 4096) {
        const int* dst; const int* src; const float* w; int n; int ndst; int* cur; unsigned int* rec;
        int within;
        if (b < 2048) { dst = p.dstA; src = p.srcA; w = p.wA; n = p.nA; ndst = p.ndA; cur = p.curA; rec = p.recA; within = b; }
        else          { dst = p.dstB; src = p.srcB; w = p.wB; n = p.nB; ndst = p.ndB; cur = p.curB; rec = p.recB; within = b - 2048; }
        const int r  = within & 7;          // dst-range == XCD group (blockIdx%8)
        const int lb = within >> 3;         // 0..255 within range-group
        const int rsz = (ndst + 7) >> 3;
        const int d0 = r * rsz;
        const int d1 = (d0 + rsz < ndst) ? d0 + rsz : ndst;
        for (int e = lb * 256 + tid; e < n; e += 256 * 256) {
            int d = __builtin_nontemporal_load(dst + e);   // nt: don't pollute L2
            if (d >= d0 && d < d1) {
                int pos = atomicAdd(&cur[d], 1);
                float wv = __builtin_nontemporal_load(w + e);
                unsigned int sv = (unsigned int)__builtin_nontemporal_load(src + e);
                unsigned int wq = (unsigned int)fminf(rintf(wv * 32768.0f), 32767.0f);
                rec[pos] = (sv << 15) | wq;
            }
        }
    } else if (b < 6144) {
        int total = p.n8u + p.n8m;
        for (int i = (b - 4096) * 256 + tid; i < total; i += 2048 * 256) {
            const float* in; __bf16* out; int j;
            if (i < p.n8u) { in = p.xu; out = p.xu_bf; j = i; }
            else           { in = p.xm; out = p.xm_bf; j = i - p.n8u; }
            float4 x = *reinterpret_cast<const float4*>(in + (size_t)j * 8);
            float4 y = *reinterpret_cast<const float4*>(in + (size_t)j * 8 + 4);
            bf16x8 v;
            v[0] = (__bf16)x.x; v[1] = (__bf16)x.y; v[2] = (__bf16)x.z; v[3] = (__bf16)x.w;
            v[4] = (__bf16)y.x; v[5] = (__bf16)y.y; v[6] = (__bf16)y.z; v[7] = (__bf16)y.w;
            *reinterpret_cast<bf16x8*>(out + (size_t)j * 8) = v;
        }
    } else {
        // packed fragment-major weights: frag f = ncg*16+kc; lane l bytes f*1024+l*16
        int t = (b - 6144) * 256 + tid;          // 0 .. 524287
        int set = t >> 17;
        int e2  = t & 131071;
        int f = e2 >> 9;
        int e = e2 & 511;
        int l = e >> 3;
        int j = e & 7;
        int ncg = f >> 4;
        int kc  = f & 15;
        int col = ncg * 16 + (l & 15);
        int k   = kc * 32 + (l >> 4) * 8 + j;
        float v = (k < 256) ? p.Wl[set][(size_t)k * 256 + col]
                            : p.Wr[set][(size_t)(k - 256) * 256 + col];
        p.wout[set][e2] = (__bf16)v;
    }
}

// ---------------------------------------------------------------------------
// Dual aggregation (movie side blocks [0,nbA), user side rest): one wave per
// dst row; 2 edges per wave-step (32 lanes x 16B), 16 edges in flight;
// cross-half combine via shfl_xor(32). Records are 4B packed (src<<15 | wq).
// ---------------------------------------------------------------------------
__global__ __launch_bounds__(256) void agg_dual(
    const __bf16* __restrict__ xA, const unsigned int* __restrict__ recA,
    const int* __restrict__ rpA, __bf16* __restrict__ meanA, int ndA, int nbA,
    const __bf16* __restrict__ xB, const unsigned int* __restrict__ recB,
    const int* __restrict__ rpB, __bf16* __restrict__ meanB, int ndB)
{
    const __bf16* xsrc; const unsigned int* rec; const int* rowptr; __bf16* mean; int ndst; int lb;
    if ((int)blockIdx.x < nbA) { xsrc = xA; rec = recA; rowptr = rpA; mean = meanA; ndst = ndA; lb = blockIdx.x; }
    else                       { xsrc = xB; rec = recB; rowptr = rpB; mean = meanB; ndst = ndB; lb = blockIdx.x - nbA; }
    int wid  = lb * 4 + (threadIdx.x >> 6);
    int lane = threadIdx.x & 63;
    if (wid >= ndst) return;
    int beg = rowptr[wid], end = rowptr[wid + 1];
    const int half = lane >> 5, hl = lane & 31;
    const __bf16* xcol = xsrc + hl * 8;
    const float wscale = 1.0f / 32768.0f;
    float acc[8];
    #pragma unroll
    for (int i = 0; i < 8; ++i) acc[i] = 0.f;

    int j0 = beg;
    while (j0 < end) {
        int m = end - j0; if (m > 64) m = 64;
        unsigned int rl = (lane < m) ? rec[j0 + lane] : 0u;
        int t = 0;
        for (; t + 16 <= m; t += 16) {
            bf16x8 v[8]; float wt[8];
            #pragma unroll
            for (int u = 0; u < 8; ++u) {
                int tt = t + u * 2;
                unsigned int r0 = (unsigned int)__builtin_amdgcn_readlane((int)rl, tt);
                unsigned int r1 = (unsigned int)__builtin_amdgcn_readlane((int)rl, tt + 1);
                unsigned int rr = half ? r1 : r0;
                wt[u] = (float)(rr & 32767u) * wscale;
                v[u] = *reinterpret_cast<const bf16x8*>(xcol + (size_t)(rr >> 15) * DFEAT);
            }
            #pragma unroll
            for (int u = 0; u < 8; ++u)
                #pragma unroll
                for (int i = 0; i < 8; ++i) acc[i] += wt[u] * (float)v[u][i];
        }
        for (; t < m; t += 2) {
            unsigned int r0 = (unsigned int)__builtin_amdgcn_readlane((int)rl, t);
            unsigned int r1 = (unsigned int)__builtin_amdgcn_readlane((int)rl, (t + 1 < 64) ? t + 1 : 63);
            unsigned int rr = half ? r1 : r0;
            float wv2 = (float)(rr & 32767u) * wscale;
            if (half && t + 1 >= m) wv2 = 0.f;
            bf16x8 v = *reinterpret_cast<const bf16x8*>(xcol + (size_t)(rr >> 15) * DFEAT);
            #pragma unroll
            for (int i = 0; i < 8; ++i) acc[i] += wv2 * (float)v[i];
        }
        j0 += m;
    }

    #pragma unroll
    for (int i = 0; i < 8; ++i) acc[i] += __shfl_xor(acc[i], 32);
    float inv = (end > beg) ? 1.0f / (float)(end - beg) : 0.0f;
    if (half == 0) {
        bf16x8 o;
        #pragma unroll
        for (int i = 0; i < 8; ++i) o[i] = (__bf16)(acc[i] * inv);
        *reinterpret_cast<bf16x8*>(mean + (size_t)wid * DFEAT + hl * 8) = o;
    }
}

// ---------------------------------------------------------------------------
// Dual MFMA GEMM, 2-deep pipeline (R10 structure): out = epi(A@Wl + B@Wr + b)
// ---------------------------------------------------------------------------
struct GemmSide {
    const __bf16* A; const __bf16* B; const __bf16* W;
    const float* bias; const __bf16* resid; void* out; int n;
};

template<int EPI>
__global__ __launch_bounds__(256) void gemm_dual(GemmSide s0, GemmSide s1, int nb0) {
    __shared__ char sA[3][64 * 128];      // 3 x 8 KB

    const GemmSide& S = ((int)blockIdx.x < nb0) ? s0 : s1;
    const int lblk = ((int)blockIdx.x < nb0) ? blockIdx.x : blockIdx.x - nb0;
    const __bf16* __restrict__ Amat = S.A;
    const __bf16* __restrict__ Bmat = S.B;
    const char* Wb = reinterpret_cast<const char*>(S.W);
    const int n = S.n;

    const int tid  = threadIdx.x;
    const int lane = tid & 63;
    const int wv   = tid >> 6;
    const int lo   = lane & 15;
    const int hi   = lane >> 4;
    const int brow = lblk * 64;
    const int wcol = wv * 64;
    const int nm1  = n - 1;

    f32x4 acc[4][4];
    #pragma unroll
    for (int i = 0; i < 4; ++i)
        #pragma unroll
        for (int j = 0; j < 4; ++j) acc[i][j] = (f32x4){0.f, 0.f, 0.f, 0.f};

    auto stage = [&](int chunk, int buf) {
        const __bf16* mat = (chunk < 4) ? Amat : Bmat;
        const int kbyte = (chunk & 3) * 128;
        #pragma unroll
        for (int q = 0; q < 2; ++q) {
            int s = q * 256 + tid;
            int r = s >> 3, sub = s & 7;
            int grow = brow + r; if (grow > nm1) grow = nm1;
            int srcoff = (sub * 16) ^ ((r & 7) << 4);
            const char* g = reinterpret_cast<const char*>(mat) + (size_t)grow * 512 + kbyte + srcoff;
            __builtin_amdgcn_global_load_lds(
                (const __attribute__((address_space(1))) void*)g,
                (__attribute__((address_space(3))) void*)(sA[buf] + s * 16), 16, 0, 0);
        }
    };

    const int lb = lane * 16;
    bf16x8 bqA[2][4], bqB[2][4];
    auto loadB = [&](int chunk, bf16x8 (&dst)[2][4]) {
        #pragma unroll
        for (int ks = 0; ks < 2; ++ks)
            #pragma unroll
            for (int nn = 0; nn < 4; ++nn)
                dst[ks][nn] = *reinterpret_cast<const bf16x8*>(
                    Wb + (size_t)(((wv * 4 + nn) * 16 + chunk * 2 + ks) << 10) + lb);
    };

    stage(0, 0);
    stage(1, 1);
    loadB(0, bqA);

    #pragma unroll
    for (int c = 0; c < 8; ++c) {
        asm volatile("s_waitcnt vmcnt(10)" ::: "memory");
        __builtin_amdgcn_s_barrier();
        __builtin_amdgcn_sched_barrier(0);
        if (c < 6) stage(c + 2, (c + 2) % 3);
        const int cur = c % 3;
        auto compute = [&](bf16x8 (&bq)[2][4]) {
            #pragma unroll
            for (int ks = 0; ks < 2; ++ks) {
                const int kb = ks * 64 + hi * 16;
                #pragma unroll
                for (int mm = 0; mm < 4; ++mm) {
                    int r = mm * 16 + lo;
                    bf16x8 a = *reinterpret_cast<const bf16x8*>(
                        sA[cur] + r * 128 + (kb ^ ((r & 7) << 4)));
                    #pragma unroll
                    for (int nn = 0; nn < 4; ++nn)
                        acc[mm][nn] = __builtin_amdgcn_mfma_f32_16x16x32_bf16(
                            a, bq[ks][nn], acc[mm][nn], 0, 0, 0);
                }
            }
        };
        if ((c & 1) == 0) { if (c < 7) loadB(c + 1, bqB); compute(bqA); }
        else              { if (c < 7) loadB(c + 1, bqA); compute(bqB); }
    }

    #pragma unroll
    for (int mm = 0; mm < 4; ++mm) {
        #pragma unroll
        for (int nn = 0; nn < 4; ++nn) {
            int col = wcol + nn * 16 + lo;
            float bv2 = S.bias[col];
            #pragma unroll
            for (int r = 0; r < 4; ++r) {
                int grow = brow + mm * 16 + hi * 4 + r;
                if (grow >= n) continue;
                float v = acc[mm][nn][r] + bv2;
                if (EPI == 1) {
                    float rv = (float)S.resid[(size_t)grow * DFEAT + col];
                    ((__bf16*)S.out)[(size_t)grow * DFEAT + col] =
                        (__bf16)(rv + fmaxf(v, 0.f));
                } else {
                    ((float*)S.out)[(size_t)grow * DFEAT + col] = v;
                }
            }
        }
    }
}

// ---------------------------------------------------------------------------
extern "C" void kernel_launch(void* const* d_in, const int* in_sizes, int n_in,
                              void* d_out, int out_size, void* d_ws, size_t ws_size,
                              hipStream_t stream) {
    const float* x_user  = (const float*)d_in[0];
    const float* x_movie = (const float*)d_in[1];
    const int*   src_um  = (const int*)d_in[2];
    const int*   dst_um  = (const int*)d_in[3];
    const float* w_um    = (const float*)d_in[4];
    const int*   src_mu  = (const int*)d_in[5];
    const int*   dst_mu  = (const int*)d_in[6];
    const float* w_mu    = (const float*)d_in[7];
    const float* c1_um_Wl = (const float*)d_in[8];
    const float* c1_um_Wr = (const float*)d_in[9];
    const float* c1_um_b  = (const float*)d_in[10];
    const float* c1_mu_Wl = (const float*)d_in[11];
    const float* c1_mu_Wr = (const float*)d_in[12];
    const float* c1_mu_b  = (const float*)d_in[13];
    const float* c2_um_Wl = (const float*)d_in[14];
    const float* c2_um_Wr = (const float*)d_in[15];
    const float* c2_um_b  = (const float*)d_in[16];
    const float* c2_mu_Wl = (const float*)d_in[17];
    const float* c2_mu_Wr = (const float*)d_in[18];
    const float* c2_mu_b  = (const float*)d_in[19];

    const int NU = in_sizes[0] / DFEAT;
    const int NM = in_sizes[1] / DFEAT;
    const int E_um = in_sizes[2];
    const int E_mu = in_sizes[5];

    char* p = (char*)d_ws;
    auto carve = [&](size_t bytes) { char* r = p; p += (bytes + 255) & ~(size_t)255; return r; };
    int* rowptr_m = (int*)carve((size_t)(NM + 1) * 4);
    int* rowptr_u = (int*)carve((size_t)(NU + 1) * 4);
    int* cursor_m = (int*)carve((size_t)NM * 4);
    int* cursor_u = (int*)carve((size_t)NU * 4);
    int* bsum_m   = (int*)carve(64 * 4);
    int* bsum_u   = (int*)carve(64 * 4);
    __bf16* xu_bf = (__bf16*)carve((size_t)NU * DFEAT * 2);
    __bf16* xm_bf = (__bf16*)carve((size_t)NM * DFEAT * 2);
    __bf16* ru_bf = (__bf16*)carve((size_t)NU * DFEAT * 2);
    __bf16* rm_bf = (__bf16*)carve((size_t)NM * DFEAT * 2);
    __bf16* wt_c1um = (__bf16*)carve(256 * 512 * 2);
    __bf16* wt_c1mu = (__bf16*)carve(256 * 512 * 2);
    __bf16* wt_c2um = (__bf16*)carve(256 * 512 * 2);
    __bf16* wt_c2mu = (__bf16*)carve(256 * 512 * 2);

    // 4B packed records in the dead tail of d_out (consumed before final writes)
    char* dtail = (char*)d_out + (size_t)(NU + NM) * DFEAT * 2;
    unsigned int* rec_m = (unsigned int*)(dtail);
    unsigned int* rec_u = (unsigned int*)(dtail + (size_t)E_um * 4);

    __bf16* mean1_u = (__bf16*)d_out;
    __bf16* mean1_m = (__bf16*)d_out + (size_t)NU * DFEAT;
    float* out_user  = (float*)d_out;
    float* out_movie = (float*)d_out + (size_t)NU * DFEAT;

    // ---- CSR build ----
    size_t msz = ((((size_t)(NM + 1) * 4) + 255) & ~(size_t)255) + (size_t)(NU + 1) * 4;
    hipMemsetAsync(rowptr_m, 0, msz, stream);   // covers rowptr_m + rowptr_u
    hist2_kernel<<<4096, 256, 0, stream>>>(dst_um, E_um, rowptr_m, dst_mu, E_mu, rowptr_u);
    const int nbM = (NM + 1 + 2047) / 2048;
    const int nbU = (NU + 1 + 2047) / 2048;
    scan_block2<<<nbM + nbU, 256, 0, stream>>>(rowptr_m, NM + 1, bsum_m, rowptr_u, NU + 1, bsum_u, nbM);
    scan_sums2<<<1, 128, 0, stream>>>(bsum_m, nbM, bsum_u, nbU);
    scan_add2<<<nbM + nbU, 256, 0, stream>>>(rowptr_m, NM + 1, bsum_m, cursor_m,
                                             rowptr_u, NU + 1, bsum_u, cursor_u, nbM);

    // ---- mega prep: XCD-partitioned fill (nt edge reads) + bf16 + weights ----
    PrepArgs pa;
    pa.dstA = dst_um; pa.srcA = src_um; pa.wA = w_um; pa.nA = E_um; pa.ndA = NM; pa.curA = cursor_m; pa.recA = rec_m;
    pa.dstB = dst_mu; pa.srcB = src_mu; pa.wB = w_mu; pa.nB = E_mu; pa.ndB = NU; pa.curB = cursor_u; pa.recB = rec_u;
    pa.xu = x_user;  pa.xu_bf = xu_bf; pa.n8u = NU * DFEAT / 8;
    pa.xm = x_movie; pa.xm_bf = xm_bf; pa.n8m = NM * DFEAT / 8;
    pa.Wl[0] = c1_um_Wl; pa.Wr[0] = c1_um_Wr; pa.wout[0] = wt_c1um;
    pa.Wl[1] = c1_mu_Wl; pa.Wr[1] = c1_mu_Wr; pa.wout[1] = wt_c1mu;
    pa.Wl[2] = c2_um_Wl; pa.Wr[2] = c2_um_Wr; pa.wout[2] = wt_c2um;
    pa.Wl[3] = c2_mu_Wl; pa.Wr[3] = c2_mu_Wr; pa.wout[3] = wt_c2mu;
    mega_prep<<<8192, 256, 0, stream>>>(pa);

    const int gaM = (NM + 3) / 4, gaU = (NU + 3) / 4;
    const int gbM = (NM + 63) / 64, gbU = (NU + 63) / 64;

    // ---- layer 1 ----
    agg_dual<<<gaM + gaU, 256, 0, stream>>>(xu_bf, rec_m, rowptr_m, mean1_m, NM, gaM,
                                            xm_bf, rec_u, rowptr_u, mean1_u, NU);
    GemmSide g1m = {mean1_m, xm_bf, wt_c1um, c1_um_b, xm_bf, rm_bf, NM};
    GemmSide g1u = {mean1_u, xu_bf, wt_c1mu, c1_mu_b, xu_bf, ru_bf, NU};
    gemm_dual<1><<<gbM + gbU, 256, 0, stream>>>(g1m, g1u, gbM);

    // ---- layer 2 (means reuse dead x_bf buffers) ----
    __bf16* mean2_m = xm_bf;
    __bf16* mean2_u = xu_bf;
    agg_dual<<<gaM + gaU, 256, 0, stream>>>(ru_bf, rec_m, rowptr_m, mean2_m, NM, gaM,
                                            rm_bf, rec_u, rowptr_u, mean2_u, NU);
    GemmSide g2m = {mean2_m, rm_bf, wt_c2um, c2_um_b, nullptr, out_movie, NM};
    GemmSide g2u = {mean2_u, ru_bf, wt_c2mu, c2_mu_b, nullptr, out_user, NU};
    gemm_dual<0><<<gbM + gbU, 256, 0, stream>>>(g2m, g2u, gbM);
}

// Round 19
// 617.240 us; speedup vs baseline: 3.0954x; 1.0025x over previous
//
#include <hip/hip_runtime.h>
#include <hip/hip_bf16.h>

#define DFEAT 256

typedef __bf16 bf16x8 __attribute__((ext_vector_type(8)));
typedef float  f32x4  __attribute__((ext_vector_type(4)));

// ---------------------------------------------------------------------------
// CSR build: histogram -> hierarchical scan (cursor written in scan_add)
// ---------------------------------------------------------------------------
__global__ void hist2_kernel(const int* __restrict__ dA, int nA, int* __restrict__ PA,
                             const int* __restrict__ dB, int nB, int* __restrict__ PB) {
    int half = gridDim.x >> 1;
    if (blockIdx.x < half) {
        for (int e = blockIdx.x * blockDim.x + threadIdx.x; e < nA; e += half * blockDim.x)
            atomicAdd(&PA[dA[e] + 1], 1);
    } else {
        for (int e = (blockIdx.x - half) * blockDim.x + threadIdx.x; e < nB; e += half * blockDim.x)
            atomicAdd(&PB[dB[e] + 1], 1);
    }
}

__global__ __launch_bounds__(256) void scan_block2(
    int* __restrict__ am, int nm, int* __restrict__ bsm,
    int* __restrict__ au, int nu, int* __restrict__ bsu, int nbM)
{
    __shared__ int wsum[4];
    int* a; int n; int* bsum; int bid;
    if ((int)blockIdx.x < nbM) { a = am; n = nm; bsum = bsm; bid = blockIdx.x; }
    else                       { a = au; n = nu; bsum = bsu; bid = blockIdx.x - nbM; }
    const int tid = threadIdx.x;
    const int lane = tid & 63, wv = tid >> 6;
    const int idx = bid * 2048 + tid * 8;
    int v[8];
    #pragma unroll
    for (int i = 0; i < 8; ++i) v[i] = (idx + i < n) ? a[idx + i] : 0;
    #pragma unroll
    for (int i = 1; i < 8; ++i) v[i] += v[i - 1];
    int tsum = v[7];
    int sc = tsum;
    #pragma unroll
    for (int off = 1; off < 64; off <<= 1) {
        int t = __shfl_up(sc, off);
        if (lane >= off) sc += t;
    }
    if (lane == 63) wsum[wv] = sc;
    __syncthreads();
    int wadd = 0;
    for (int w2 = 0; w2 < wv; ++w2) wadd += wsum[w2];
    int texcl = sc - tsum + wadd;
    #pragma unroll
    for (int i = 0; i < 8; ++i)
        if (idx + i < n) a[idx + i] = v[i] + texcl;
    if (tid == 255) bsum[bid] = sc + wadd;
}

__global__ void scan_sums2(int* __restrict__ bsm, int nbM, int* __restrict__ bsu, int nbU) {
    int wv = threadIdx.x >> 6;
    int lane = threadIdx.x & 63;
    int* bs = wv ? bsu : bsm;
    int nb  = wv ? nbU : nbM;
    int v = (lane < nb) ? bs[lane] : 0;
    #pragma unroll
    for (int off = 1; off < 64; off <<= 1) {
        int t = __shfl_up(v, off);
        if (lane >= off) v += t;
    }
    if (lane < nb) bs[lane] = v;
}

// adds block prefixes AND writes the cursor copy (cursor[d] = rowptr[d])
__global__ __launch_bounds__(256) void scan_add2(
    int* __restrict__ am, int nm, const int* __restrict__ bsm, int* __restrict__ curM,
    int* __restrict__ au, int nu, const int* __restrict__ bsu, int* __restrict__ curU, int nbM)
{
    int* a; int n; const int* bsum; int* cur; int bid;
    if ((int)blockIdx.x < nbM) { a = am; n = nm; bsum = bsm; cur = curM; bid = blockIdx.x; }
    else                       { a = au; n = nu; bsum = bsu; cur = curU; bid = blockIdx.x - nbM; }
    int add = (bid == 0) ? 0 : bsum[bid - 1];
    int idx = bid * 2048 + threadIdx.x * 8;
    #pragma unroll
    for (int i = 0; i < 8; ++i) {
        if (idx + i < n) {
            int v = a[idx + i] + add;
            if (bid > 0) a[idx + i] = v;
            if (idx + i < n - 1) cur[idx + i] = v;
        }
    }
}

// ---------------------------------------------------------------------------
// Mega-prep: [0,4096) XCD-partitioned edge fill (4B packed records) |
// [4096,6144) f32->bf16 | [6144,8192) packed weight transpose.
// ALL streaming traffic (edge reads, conversion loads/stores, weight
// loads/stores) is NON-TEMPORAL so it can't evict the partially-filled
// record lines from the per-XCD L2 -> record lines accumulate ~16 stores
// before one writeback. Record stores stay cached.
// ---------------------------------------------------------------------------
struct PrepArgs {
    const int* dstA; const int* srcA; const float* wA; int nA; int ndA;
    int* curA; unsigned int* recA;
    const int* dstB; const int* srcB; const float* wB; int nB; int ndB;
    int* curB; unsigned int* recB;
    const float* xu; __bf16* xu_bf; int n8u;
    const float* xm; __bf16* xm_bf; int n8m;
    const float* Wl[4]; const float* Wr[4]; __bf16* wout[4];
};

__global__ __launch_bounds__(256) void mega_prep(PrepArgs p) {
    const int b = blockIdx.x;
    const int tid = threadIdx.x;
    if (b < 4096) {
        const int* dst; const int* src; const float* w; int n; int ndst; int* cur; unsigned int* rec;
        int within;
        if (b < 2048) { dst = p.dstA; src = p.srcA; w = p.wA; n = p.nA; ndst = p.ndA; cur = p.curA; rec = p.recA; within = b; }
        else          { dst = p.dstB; src = p.srcB; w = p.wB; n = p.nB; ndst = p.ndB; cur = p.curB; rec = p.recB; within = b - 2048; }
        const int r  = within & 7;          // dst-range == XCD group (blockIdx%8)
        const int lb = within >> 3;         // 0..255 within range-group
        const int rsz = (ndst + 7) >> 3;
        const int d0 = r * rsz;
        const int d1 = (d0 + rsz < ndst) ? d0 + rsz : ndst;
        for (int e = lb * 256 + tid; e < n; e += 256 * 256) {
            int d = __builtin_nontemporal_load(dst + e);   // nt: don't pollute L2
            if (d >= d0 && d < d1) {
                int pos = atomicAdd(&cur[d], 1);
                float wv = __builtin_nontemporal_load(w + e);
                unsigned int sv = (unsigned int)__builtin_nontemporal_load(src + e);
                unsigned int wq = (unsigned int)fminf(rintf(wv * 32768.0f), 32767.0f);
                rec[pos] = (sv << 15) | wq;
            }
        }
    } else if (b < 6144) {
        int total = p.n8u + p.n8m;
        for (int i = (b - 4096) * 256 + tid; i < total; i += 2048 * 256) {
            const float* in; __bf16* out; int j;
            if (i < p.n8u) { in = p.xu; out = p.xu_bf; j = i; }
            else           { in = p.xm; out = p.xm_bf; j = i - p.n8u; }
            const f32x4* p4 = reinterpret_cast<const f32x4*>(in + (size_t)j * 8);
            f32x4 x = __builtin_nontemporal_load(p4);
            f32x4 y = __builtin_nontemporal_load(p4 + 1);
            bf16x8 v;
            v[0] = (__bf16)x[0]; v[1] = (__bf16)x[1]; v[2] = (__bf16)x[2]; v[3] = (__bf16)x[3];
            v[4] = (__bf16)y[0]; v[5] = (__bf16)y[1]; v[6] = (__bf16)y[2]; v[7] = (__bf16)y[3];
            __builtin_nontemporal_store(v, reinterpret_cast<bf16x8*>(out + (size_t)j * 8));
        }
    } else {
        // packed fragment-major weights: frag f = ncg*16+kc; lane l bytes f*1024+l*16
        int t = (b - 6144) * 256 + tid;          // 0 .. 524287
        int set = t >> 17;
        int e2  = t & 131071;
        int f = e2 >> 9;
        int e = e2 & 511;
        int l = e >> 3;
        int j = e & 7;
        int ncg = f >> 4;
        int kc  = f & 15;
        int col = ncg * 16 + (l & 15);
        int k   = kc * 32 + (l >> 4) * 8 + j;
        const float* wp = (k < 256) ? &p.Wl[set][(size_t)k * 256 + col]
                                    : &p.Wr[set][(size_t)(k - 256) * 256 + col];
        float v = __builtin_nontemporal_load(wp);
        __builtin_nontemporal_store((__bf16)v, &p.wout[set][e2]);
    }
}

// ---------------------------------------------------------------------------
// Dual aggregation (movie side blocks [0,nbA), user side rest): one wave per
// dst row; 2 edges per wave-step (32 lanes x 16B), 16 edges in flight;
// cross-half combine via shfl_xor(32). Records are 4B packed (src<<15 | wq).
// ---------------------------------------------------------------------------
__global__ __launch_bounds__(256) void agg_dual(
    const __bf16* __restrict__ xA, const unsigned int* __restrict__ recA,
    const int* __restrict__ rpA, __bf16* __restrict__ meanA, int ndA, int nbA,
    const __bf16* __restrict__ xB, const unsigned int* __restrict__ recB,
    const int* __restrict__ rpB, __bf16* __restrict__ meanB, int ndB)
{
    const __bf16* xsrc; const unsigned int* rec; const int* rowptr; __bf16* mean; int ndst; int lb;
    if ((int)blockIdx.x < nbA) { xsrc = xA; rec = recA; rowptr = rpA; mean = meanA; ndst = ndA; lb = blockIdx.x; }
    else                       { xsrc = xB; rec = recB; rowptr = rpB; mean = meanB; ndst = ndB; lb = blockIdx.x - nbA; }
    int wid  = lb * 4 + (threadIdx.x >> 6);
    int lane = threadIdx.x & 63;
    if (wid >= ndst) return;
    int beg = rowptr[wid], end = rowptr[wid + 1];
    const int half = lane >> 5, hl = lane & 31;
    const __bf16* xcol = xsrc + hl * 8;
    const float wscale = 1.0f / 32768.0f;
    float acc[8];
    #pragma unroll
    for (int i = 0; i < 8; ++i) acc[i] = 0.f;

    int j0 = beg;
    while (j0 < end) {
        int m = end - j0; if (m > 64) m = 64;
        unsigned int rl = (lane < m) ? rec[j0 + lane] : 0u;
        int t = 0;
        for (; t + 16 <= m; t += 16) {
            bf16x8 v[8]; float wt[8];
            #pragma unroll
            for (int u = 0; u < 8; ++u) {
                int tt = t + u * 2;
                unsigned int r0 = (unsigned int)__builtin_amdgcn_readlane((int)rl, tt);
                unsigned int r1 = (unsigned int)__builtin_amdgcn_readlane((int)rl, tt + 1);
                unsigned int rr = half ? r1 : r0;
                wt[u] = (float)(rr & 32767u) * wscale;
                v[u] = *reinterpret_cast<const bf16x8*>(xcol + (size_t)(rr >> 15) * DFEAT);
            }
            #pragma unroll
            for (int u = 0; u < 8; ++u)
                #pragma unroll
                for (int i = 0; i < 8; ++i) acc[i] += wt[u] * (float)v[u][i];
        }
        for (; t < m; t += 2) {
            unsigned int r0 = (unsigned int)__builtin_amdgcn_readlane((int)rl, t);
            unsigned int r1 = (unsigned int)__builtin_amdgcn_readlane((int)rl, (t + 1 < 64) ? t + 1 : 63);
            unsigned int rr = half ? r1 : r0;
            float wv2 = (float)(rr & 32767u) * wscale;
            if (half && t + 1 >= m) wv2 = 0.f;
            bf16x8 v = *reinterpret_cast<const bf16x8*>(xcol + (size_t)(rr >> 15) * DFEAT);
            #pragma unroll
            for (int i = 0; i < 8; ++i) acc[i] += wv2 * (float)v[i];
        }
        j0 += m;
    }

    #pragma unroll
    for (int i = 0; i < 8; ++i) acc[i] += __shfl_xor(acc[i], 32);
    float inv = (end > beg) ? 1.0f / (float)(end - beg) : 0.0f;
    if (half == 0) {
        bf16x8 o;
        #pragma unroll
        for (int i = 0; i < 8; ++i) o[i] = (__bf16)(acc[i] * inv);
        *reinterpret_cast<bf16x8*>(mean + (size_t)wid * DFEAT + hl * 8) = o;
    }
}

// ---------------------------------------------------------------------------
// Dual MFMA GEMM, 2-deep pipeline (R10 structure): out = epi(A@Wl + B@Wr + b)
// ---------------------------------------------------------------------------
struct GemmSide {
    const __bf16* A; const __bf16* B; const __bf16* W;
    const float* bias; const __bf16* resid; void* out; int n;
};

template<int EPI>
__global__ __launch_bounds__(256) void gemm_dual(GemmSide s0, GemmSide s1, int nb0) {
    __shared__ char sA[3][64 * 128];      // 3 x 8 KB

    const GemmSide& S = ((int)blockIdx.x < nb0) ? s0 : s1;
    const int lblk = ((int)blockIdx.x < nb0) ? blockIdx.x : blockIdx.x - nb0;
    const __bf16* __restrict__ Amat = S.A;
    const __bf16* __restrict__ Bmat = S.B;
    const char* Wb = reinterpret_cast<const char*>(S.W);
    const int n = S.n;

    const int tid  = threadIdx.x;
    const int lane = tid & 63;
    const int wv   = tid >> 6;
    const int lo   = lane & 15;
    const int hi   = lane >> 4;
    const int brow = lblk * 64;
    const int wcol = wv * 64;
    const int nm1  = n - 1;

    f32x4 acc[4][4];
    #pragma unroll
    for (int i = 0; i < 4; ++i)
        #pragma unroll
        for (int j = 0; j < 4; ++j) acc[i][j] = (f32x4){0.f, 0.f, 0.f, 0.f};

    auto stage = [&](int chunk, int buf) {
        const __bf16* mat = (chunk < 4) ? Amat : Bmat;
        const int kbyte = (chunk & 3) * 128;
        #pragma unroll
        for (int q = 0; q < 2; ++q) {
            int s = q * 256 + tid;
            int r = s >> 3, sub = s & 7;
            int grow = brow + r; if (grow > nm1) grow = nm1;
            int srcoff = (sub * 16) ^ ((r & 7) << 4);
            const char* g = reinterpret_cast<const char*>(mat) + (size_t)grow * 512 + kbyte + srcoff;
            __builtin_amdgcn_global_load_lds(
                (const __attribute__((address_space(1))) void*)g,
                (__attribute__((address_space(3))) void*)(sA[buf] + s * 16), 16, 0, 0);
        }
    };

    const int lb = lane * 16;
    bf16x8 bqA[2][4], bqB[2][4];
    auto loadB = [&](int chunk, bf16x8 (&dst)[2][4]) {
        #pragma unroll
        for (int ks = 0; ks < 2; ++ks)
            #pragma unroll
            for (int nn = 0; nn < 4; ++nn)
                dst[ks][nn] = *reinterpret_cast<const bf16x8*>(
                    Wb + (size_t)(((wv * 4 + nn) * 16 + chunk * 2 + ks) << 10) + lb);
    };

    stage(0, 0);
    stage(1, 1);
    loadB(0, bqA);

    #pragma unroll
    for (int c = 0; c < 8; ++c) {
        asm volatile("s_waitcnt vmcnt(10)" ::: "memory");
        __builtin_amdgcn_s_barrier();
        __builtin_amdgcn_sched_barrier(0);
        if (c < 6) stage(c + 2, (c + 2) % 3);
        const int cur = c % 3;
        auto compute = [&](bf16x8 (&bq)[2][4]) {
            #pragma unroll
            for (int ks = 0; ks < 2; ++ks) {
                const int kb = ks * 64 + hi * 16;
                #pragma unroll
                for (int mm = 0; mm < 4; ++mm) {
                    int r = mm * 16 + lo;
                    bf16x8 a = *reinterpret_cast<const bf16x8*>(
                        sA[cur] + r * 128 + (kb ^ ((r & 7) << 4)));
                    #pragma unroll
                    for (int nn = 0; nn < 4; ++nn)
                        acc[mm][nn] = __builtin_amdgcn_mfma_f32_16x16x32_bf16(
                            a, bq[ks][nn], acc[mm][nn], 0, 0, 0);
                }
            }
        };
        if ((c & 1) == 0) { if (c < 7) loadB(c + 1, bqB); compute(bqA); }
        else              { if (c < 7) loadB(c + 1, bqA); compute(bqB); }
    }

    #pragma unroll
    for (int mm = 0; mm < 4; ++mm) {
        #pragma unroll
        for (int nn = 0; nn < 4; ++nn) {
            int col = wcol + nn * 16 + lo;
            float bv2 = S.bias[col];
            #pragma unroll
            for (int r = 0; r < 4; ++r) {
                int grow = brow + mm * 16 + hi * 4 + r;
                if (grow >= n) continue;
                float v = acc[mm][nn][r] + bv2;
                if (EPI == 1) {
                    float rv = (float)S.resid[(size_t)grow * DFEAT + col];
                    ((__bf16*)S.out)[(size_t)grow * DFEAT + col] =
                        (__bf16)(rv + fmaxf(v, 0.f));
                } else {
                    ((float*)S.out)[(size_t)grow * DFEAT + col] = v;
                }
            }
        }
    }
}

// ---------------------------------------------------------------------------
extern "C" void kernel_launch(void* const* d_in, const int* in_sizes, int n_in,
                              void* d_out, int out_size, void* d_ws, size_t ws_size,
                              hipStream_t stream) {
    const float* x_user  = (const float*)d_in[0];
    const float* x_movie = (const float*)d_in[1];
    const int*   src_um  = (const int*)d_in[2];
    const int*   dst_um  = (const int*)d_in[3];
    const float* w_um    = (const float*)d_in[4];
    const int*   src_mu  = (const int*)d_in[5];
    const int*   dst_mu  = (const int*)d_in[6];
    const float* w_mu    = (const float*)d_in[7];
    const float* c1_um_Wl = (const float*)d_in[8];
    const float* c1_um_Wr = (const float*)d_in[9];
    const float* c1_um_b  = (const float*)d_in[10];
    const float* c1_mu_Wl = (const float*)d_in[11];
    const float* c1_mu_Wr = (const float*)d_in[12];
    const float* c1_mu_b  = (const float*)d_in[13];
    const float* c2_um_Wl = (const float*)d_in[14];
    const float* c2_um_Wr = (const float*)d_in[15];
    const float* c2_um_b  = (const float*)d_in[16];
    const float* c2_mu_Wl = (const float*)d_in[17];
    const float* c2_mu_Wr = (const float*)d_in[18];
    const float* c2_mu_b  = (const float*)d_in[19];

    const int NU = in_sizes[0] / DFEAT;
    const int NM = in_sizes[1] / DFEAT;
    const int E_um = in_sizes[2];
    const int E_mu = in_sizes[5];

    char* p = (char*)d_ws;
    auto carve = [&](size_t bytes) { char* r = p; p += (bytes + 255) & ~(size_t)255; return r; };
    int* rowptr_m = (int*)carve((size_t)(NM + 1) * 4);
    int* rowptr_u = (int*)carve((size_t)(NU + 1) * 4);
    int* cursor_m = (int*)carve((size_t)NM * 4);
    int* cursor_u = (int*)carve((size_t)NU * 4);
    int* bsum_m   = (int*)carve(64 * 4);
    int* bsum_u   = (int*)carve(64 * 4);
    __bf16* xu_bf = (__bf16*)carve((size_t)NU * DFEAT * 2);
    __bf16* xm_bf = (__bf16*)carve((size_t)NM * DFEAT * 2);
    __bf16* ru_bf = (__bf16*)carve((size_t)NU * DFEAT * 2);
    __bf16* rm_bf = (__bf16*)carve((size_t)NM * DFEAT * 2);
    __bf16* wt_c1um = (__bf16*)carve(256 * 512 * 2);
    __bf16* wt_c1mu = (__bf16*)carve(256 * 512 * 2);
    __bf16* wt_c2um = (__bf16*)carve(256 * 512 * 2);
    __bf16* wt_c2mu = (__bf16*)carve(256 * 512 * 2);

    // 4B packed records in the dead tail of d_out (consumed before final writes)
    char* dtail = (char*)d_out + (size_t)(NU + NM) * DFEAT * 2;
    unsigned int* rec_m = (unsigned int*)(dtail);
    unsigned int* rec_u = (unsigned int*)(dtail + (size_t)E_um * 4);

    __bf16* mean1_u = (__bf16*)d_out;
    __bf16* mean1_m = (__bf16*)d_out + (size_t)NU * DFEAT;
    float* out_user  = (float*)d_out;
    float* out_movie = (float*)d_out + (size_t)NU * DFEAT;

    // ---- CSR build ----
    size_t msz = ((((size_t)(NM + 1) * 4) + 255) & ~(size_t)255) + (size_t)(NU + 1) * 4;
    (void)hipMemsetAsync(rowptr_m, 0, msz, stream);   // covers rowptr_m + rowptr_u
    hist2_kernel<<<4096, 256, 0, stream>>>(dst_um, E_um, rowptr_m, dst_mu, E_mu, rowptr_u);
    const int nbM = (NM + 1 + 2047) / 2048;
    const int nbU = (NU + 1 + 2047) / 2048;
    scan_block2<<<nbM + nbU, 256, 0, stream>>>(rowptr_m, NM + 1, bsum_m, rowptr_u, NU + 1, bsum_u, nbM);
    scan_sums2<<<1, 128, 0, stream>>>(bsum_m, nbM, bsum_u, nbU);
    scan_add2<<<nbM + nbU, 256, 0, stream>>>(rowptr_m, NM + 1, bsum_m, cursor_m,
                                             rowptr_u, NU + 1, bsum_u, cursor_u, nbM);

    // ---- mega prep: XCD-partitioned fill + nt conversions + nt weights ----
    PrepArgs pa;
    pa.dstA = dst_um; pa.srcA = src_um; pa.wA = w_um; pa.nA = E_um; pa.ndA = NM; pa.curA = cursor_m; pa.recA = rec_m;
    pa.dstB = dst_mu; pa.srcB = src_mu; pa.wB = w_mu; pa.nB = E_mu; pa.ndB = NU; pa.curB = cursor_u; pa.recB = rec_u;
    pa.xu = x_user;  pa.xu_bf = xu_bf; pa.n8u = NU * DFEAT / 8;
    pa.xm = x_movie; pa.xm_bf = xm_bf; pa.n8m = NM * DFEAT / 8;
    pa.Wl[0] = c1_um_Wl; pa.Wr[0] = c1_um_Wr; pa.wout[0] = wt_c1um;
    pa.Wl[1] = c1_mu_Wl; pa.Wr[1] = c1_mu_Wr; pa.wout[1] = wt_c1mu;
    pa.Wl[2] = c2_um_Wl; pa.Wr[2] = c2_um_Wr; pa.wout[2] = wt_c2um;
    pa.Wl[3] = c2_mu_Wl; pa.Wr[3] = c2_mu_Wr; pa.wout[3] = wt_c2mu;
    mega_prep<<<8192, 256, 0, stream>>>(pa);

    const int gaM = (NM + 3) / 4, gaU = (NU + 3) / 4;
    const int gbM = (NM + 63) / 64, gbU = (NU + 63) / 64;

    // ---- layer 1 ----
    agg_dual<<<gaM + gaU, 256, 0, stream>>>(xu_bf, rec_m, rowptr_m, mean1_m, NM, gaM,
                                            xm_bf, rec_u, rowptr_u, mean1_u, NU);
    GemmSide g1m = {mean1_m, xm_bf, wt_c1um, c1_um_b, xm_bf, rm_bf, NM};
    GemmSide g1u = {mean1_u, xu_bf, wt_c1mu, c1_mu_b, xu_bf, ru_bf, NU};
    gemm_dual<1><<<gbM + gbU, 256, 0, stream>>>(g1m, g1u, gbM);

    // ---- layer 2 (means reuse dead x_bf buffers) ----
    __bf16* mean2_m = xm_bf;
    __bf16* mean2_u = xu_bf;
    agg_dual<<<gaM + gaU, 256, 0, stream>>>(ru_bf, rec_m, rowptr_m, mean2_m, NM, gaM,
                                            rm_bf, rec_u, rowptr_u, mean2_u, NU);
    GemmSide g2m = {mean2_m, rm_bf, wt_c2um, c2_um_b, nullptr, out_movie, NM};
    GemmSide g2u = {mean2_u, ru_bf, wt_c2mu, c2_mu_b, nullptr, out_user, NU};
    gemm_dual<0><<<gbM + gbU, 256, 0, stream>>>(g2m, g2u, gbM);
}

// Round 20
// 615.634 us; speedup vs baseline: 3.1035x; 1.0026x over previous
//
#include <hip/hip_runtime.h>
#include <hip/hip_bf16.h>

#define DFEAT 256

typedef __bf16 bf16x8 __attribute__((ext_vector_type(8)));
typedef float  f32x4  __attribute__((ext_vector_type(4)));

// ---------------------------------------------------------------------------
// CSR build: histogram -> hierarchical scan (cursor written in scan_add)
// ---------------------------------------------------------------------------
__global__ void hist2_kernel(const int* __restrict__ dA, int nA, int* __restrict__ PA,
                             const int* __restrict__ dB, int nB, int* __restrict__ PB) {
    int half = gridDim.x >> 1;
    if (blockIdx.x < half) {
        for (int e = blockIdx.x * blockDim.x + threadIdx.x; e < nA; e += half * blockDim.x)
            atomicAdd(&PA[dA[e] + 1], 1);
    } else {
        for (int e = (blockIdx.x - half) * blockDim.x + threadIdx.x; e < nB; e += half * blockDim.x)
            atomicAdd(&PB[dB[e] + 1], 1);
    }
}

__global__ __launch_bounds__(256) void scan_block2(
    int* __restrict__ am, int nm, int* __restrict__ bsm,
    int* __restrict__ au, int nu, int* __restrict__ bsu, int nbM)
{
    __shared__ int wsum[4];
    int* a; int n; int* bsum; int bid;
    if ((int)blockIdx.x < nbM) { a = am; n = nm; bsum = bsm; bid = blockIdx.x; }
    else                       { a = au; n = nu; bsum = bsu; bid = blockIdx.x - nbM; }
    const int tid = threadIdx.x;
    const int lane = tid & 63, wv = tid >> 6;
    const int idx = bid * 2048 + tid * 8;
    int v[8];
    #pragma unroll
    for (int i = 0; i < 8; ++i) v[i] = (idx + i < n) ? a[idx + i] : 0;
    #pragma unroll
    for (int i = 1; i < 8; ++i) v[i] += v[i - 1];
    int tsum = v[7];
    int sc = tsum;
    #pragma unroll
    for (int off = 1; off < 64; off <<= 1) {
        int t = __shfl_up(sc, off);
        if (lane >= off) sc += t;
    }
    if (lane == 63) wsum[wv] = sc;
    __syncthreads();
    int wadd = 0;
    for (int w2 = 0; w2 < wv; ++w2) wadd += wsum[w2];
    int texcl = sc - tsum + wadd;
    #pragma unroll
    for (int i = 0; i < 8; ++i)
        if (idx + i < n) a[idx + i] = v[i] + texcl;
    if (tid == 255) bsum[bid] = sc + wadd;
}

__global__ void scan_sums2(int* __restrict__ bsm, int nbM, int* __restrict__ bsu, int nbU) {
    int wv = threadIdx.x >> 6;
    int lane = threadIdx.x & 63;
    int* bs = wv ? bsu : bsm;
    int nb  = wv ? nbU : nbM;
    int v = (lane < nb) ? bs[lane] : 0;
    #pragma unroll
    for (int off = 1; off < 64; off <<= 1) {
        int t = __shfl_up(v, off);
        if (lane >= off) v += t;
    }
    if (lane < nb) bs[lane] = v;
}

// adds block prefixes AND writes the cursor copy (cursor[d] = rowptr[d])
__global__ __launch_bounds__(256) void scan_add2(
    int* __restrict__ am, int nm, const int* __restrict__ bsm, int* __restrict__ curM,
    int* __restrict__ au, int nu, const int* __restrict__ bsu, int* __restrict__ curU, int nbM)
{
    int* a; int n; const int* bsum; int* cur; int bid;
    if ((int)blockIdx.x < nbM) { a = am; n = nm; bsum = bsm; cur = curM; bid = blockIdx.x; }
    else                       { a = au; n = nu; bsum = bsu; cur = curU; bid = blockIdx.x - nbM; }
    int add = (bid == 0) ? 0 : bsum[bid - 1];
    int idx = bid * 2048 + threadIdx.x * 8;
    #pragma unroll
    for (int i = 0; i < 8; ++i) {
        if (idx + i < n) {
            int v = a[idx + i] + add;
            if (bid > 0) a[idx + i] = v;
            if (idx + i < n - 1) cur[idx + i] = v;
        }
    }
}

// ---------------------------------------------------------------------------
// Mega-prep: [0,4096) XCD-partitioned edge fill (4B packed records) |
// [4096,6144) f32->bf16 | [6144,8192) packed weight transpose.
// All streaming traffic non-temporal; record stores cached.
// ---------------------------------------------------------------------------
struct PrepArgs {
    const int* dstA; const int* srcA; const float* wA; int nA; int ndA;
    int* curA; unsigned int* recA;
    const int* dstB; const int* srcB; const float* wB; int nB; int ndB;
    int* curB; unsigned int* recB;
    const float* xu; __bf16* xu_bf; int n8u;
    const float* xm; __bf16* xm_bf; int n8m;
    const float* Wl[4]; const float* Wr[4]; __bf16* wout[4];
};

__global__ __launch_bounds__(256) void mega_prep(PrepArgs p) {
    const int b = blockIdx.x;
    const int tid = threadIdx.x;
    if (b < 4096) {
        const int* dst; const int* src; const float* w; int n; int ndst; int* cur; unsigned int* rec;
        int within;
        if (b < 2048) { dst = p.dstA; src = p.srcA; w = p.wA; n = p.nA; ndst = p.ndA; cur = p.curA; rec = p.recA; within = b; }
        else          { dst = p.dstB; src = p.srcB; w = p.wB; n = p.nB; ndst = p.ndB; cur = p.curB; rec = p.recB; within = b - 2048; }
        const int r  = within & 7;          // dst-range == XCD group (blockIdx%8)
        const int lb = within >> 3;         // 0..255 within range-group
        const int rsz = (ndst + 7) >> 3;
        const int d0 = r * rsz;
        const int d1 = (d0 + rsz < ndst) ? d0 + rsz : ndst;
        for (int e = lb * 256 + tid; e < n; e += 256 * 256) {
            int d = __builtin_nontemporal_load(dst + e);   // nt: don't pollute L2
            if (d >= d0 && d < d1) {
                int pos = atomicAdd(&cur[d], 1);
                float wv = __builtin_nontemporal_load(w + e);
                unsigned int sv = (unsigned int)__builtin_nontemporal_load(src + e);
                unsigned int wq = (unsigned int)fminf(rintf(wv * 32768.0f), 32767.0f);
                rec[pos] = (sv << 15) | wq;
            }
        }
    } else if (b < 6144) {
        int total = p.n8u + p.n8m;
        for (int i = (b - 4096) * 256 + tid; i < total; i += 2048 * 256) {
            const float* in; __bf16* out; int j;
            if (i < p.n8u) { in = p.xu; out = p.xu_bf; j = i; }
            else           { in = p.xm; out = p.xm_bf; j = i - p.n8u; }
            const f32x4* p4 = reinterpret_cast<const f32x4*>(in + (size_t)j * 8);
            f32x4 x = __builtin_nontemporal_load(p4);
            f32x4 y = __builtin_nontemporal_load(p4 + 1);
            bf16x8 v;
            v[0] = (__bf16)x[0]; v[1] = (__bf16)x[1]; v[2] = (__bf16)x[2]; v[3] = (__bf16)x[3];
            v[4] = (__bf16)y[0]; v[5] = (__bf16)y[1]; v[6] = (__bf16)y[2]; v[7] = (__bf16)y[3];
            __builtin_nontemporal_store(v, reinterpret_cast<bf16x8*>(out + (size_t)j * 8));
        }
    } else {
        // packed fragment-major weights: frag f = ncg*16+kc; lane l bytes f*1024+l*16
        int t = (b - 6144) * 256 + tid;          // 0 .. 524287
        int set = t >> 17;
        int e2  = t & 131071;
        int f = e2 >> 9;
        int e = e2 & 511;
        int l = e >> 3;
        int j = e & 7;
        int ncg = f >> 4;
        int kc  = f & 15;
        int col = ncg * 16 + (l & 15);
        int k   = kc * 32 + (l >> 4) * 8 + j;
        const float* wp = (k < 256) ? &p.Wl[set][(size_t)k * 256 + col]
                                    : &p.Wr[set][(size_t)(k - 256) * 256 + col];
        float v = __builtin_nontemporal_load(wp);
        __builtin_nontemporal_store((__bf16)v, &p.wout[set][e2]);
    }
}

// ---------------------------------------------------------------------------
// Dual aggregation: one wave per dst row; SINGLE predicated 16-edge batch loop
// (8 gathers always in flight — low-degree rows no longer fall into a serial
// tail; OOB slots get weight 0 and gather the lane-0 record's row, L2-hot).
// Records are 4B packed (src<<15 | wq).
// ---------------------------------------------------------------------------
__global__ __launch_bounds__(256) void agg_dual(
    const __bf16* __restrict__ xA, const unsigned int* __restrict__ recA,
    const int* __restrict__ rpA, __bf16* __restrict__ meanA, int ndA, int nbA,
    const __bf16* __restrict__ xB, const unsigned int* __restrict__ recB,
    const int* __restrict__ rpB, __bf16* __restrict__ meanB, int ndB)
{
    const __bf16* xsrc; const unsigned int* rec; const int* rowptr; __bf16* mean; int ndst; int lb;
    if ((int)blockIdx.x < nbA) { xsrc = xA; rec = recA; rowptr = rpA; mean = meanA; ndst = ndA; lb = blockIdx.x; }
    else                       { xsrc = xB; rec = recB; rowptr = rpB; mean = meanB; ndst = ndB; lb = blockIdx.x - nbA; }
    int wid  = lb * 4 + (threadIdx.x >> 6);
    int lane = threadIdx.x & 63;
    if (wid >= ndst) return;
    int beg = rowptr[wid], end = rowptr[wid + 1];
    const int half = lane >> 5, hl = lane & 31;
    const __bf16* xcol = xsrc + hl * 8;
    const float wscale = 1.0f / 32768.0f;
    float acc[8];
    #pragma unroll
    for (int i = 0; i < 8; ++i) acc[i] = 0.f;

    int j0 = beg;
    while (j0 < end) {
        int m = end - j0; if (m > 64) m = 64;
        unsigned int rl = (lane < m) ? rec[j0 + lane] : 0u;
        for (int t = 0; t < m; t += 16) {
            bf16x8 v[8]; float wt[8];
            #pragma unroll
            for (int u = 0; u < 8; ++u) {
                int tt = t + u * 2;
                int l0 = tt     < 63 ? tt     : 63;
                int l1 = tt + 1 < 63 ? tt + 1 : 63;
                unsigned int r0 = (unsigned int)__builtin_amdgcn_readlane((int)rl, l0);
                unsigned int r1 = (unsigned int)__builtin_amdgcn_readlane((int)rl, l1);
                unsigned int rr = half ? r1 : r0;
                float wv = (float)(rr & 32767u) * wscale;
                if (tt + half >= m) wv = 0.f;          // predicate OOB slots
                wt[u] = wv;
                v[u] = *reinterpret_cast<const bf16x8*>(xcol + (size_t)(rr >> 15) * DFEAT);
            }
            #pragma unroll
            for (int u = 0; u < 8; ++u)
                #pragma unroll
                for (int i = 0; i < 8; ++i) acc[i] += wt[u] * (float)v[u][i];
        }
        j0 += m;
    }

    #pragma unroll
    for (int i = 0; i < 8; ++i) acc[i] += __shfl_xor(acc[i], 32);
    float inv = (end > beg) ? 1.0f / (float)(end - beg) : 0.0f;
    if (half == 0) {
        bf16x8 o;
        #pragma unroll
        for (int i = 0; i < 8; ++i) o[i] = (__bf16)(acc[i] * inv);
        *reinterpret_cast<bf16x8*>(mean + (size_t)wid * DFEAT + hl * 8) = o;
    }
}

// ---------------------------------------------------------------------------
// Dual MFMA GEMM, 2-deep pipeline (R10 structure): out = epi(A@Wl + B@Wr + b)
// ---------------------------------------------------------------------------
struct GemmSide {
    const __bf16* A; const __bf16* B; const __bf16* W;
    const float* bias; const __bf16* resid; void* out; int n;
};

template<int EPI>
__global__ __launch_bounds__(256) void gemm_dual(GemmSide s0, GemmSide s1, int nb0) {
    __shared__ char sA[3][64 * 128];      // 3 x 8 KB

    const GemmSide& S = ((int)blockIdx.x < nb0) ? s0 : s1;
    const int lblk = ((int)blockIdx.x < nb0) ? blockIdx.x : blockIdx.x - nb0;
    const __bf16* __restrict__ Amat = S.A;
    const __bf16* __restrict__ Bmat = S.B;
    const char* Wb = reinterpret_cast<const char*>(S.W);
    const int n = S.n;

    const int tid  = threadIdx.x;
    const int lane = tid & 63;
    const int wv   = tid >> 6;
    const int lo   = lane & 15;
    const int hi   = lane >> 4;
    const int brow = lblk * 64;
    const int wcol = wv * 64;
    const int nm1  = n - 1;

    f32x4 acc[4][4];
    #pragma unroll
    for (int i = 0; i < 4; ++i)
        #pragma unroll
        for (int j = 0; j < 4; ++j) acc[i][j] = (f32x4){0.f, 0.f, 0.f, 0.f};

    auto stage = [&](int chunk, int buf) {
        const __bf16* mat = (chunk < 4) ? Amat : Bmat;
        const int kbyte = (chunk & 3) * 128;
        #pragma unroll
        for (int q = 0; q < 2; ++q) {
            int s = q * 256 + tid;
            int r = s >> 3, sub = s & 7;
            int grow = brow + r; if (grow > nm1) grow = nm1;
            int srcoff = (sub * 16) ^ ((r & 7) << 4);
            const char* g = reinterpret_cast<const char*>(mat) + (size_t)grow * 512 + kbyte + srcoff;
            __builtin_amdgcn_global_load_lds(
                (const __attribute__((address_space(1))) void*)g,
                (__attribute__((address_space(3))) void*)(sA[buf] + s * 16), 16, 0, 0);
        }
    };

    const int lb = lane * 16;
    bf16x8 bqA[2][4], bqB[2][4];
    auto loadB = [&](int chunk, bf16x8 (&dst)[2][4]) {
        #pragma unroll
        for (int ks = 0; ks < 2; ++ks)
            #pragma unroll
            for (int nn = 0; nn < 4; ++nn)
                dst[ks][nn] = *reinterpret_cast<const bf16x8*>(
                    Wb + (size_t)(((wv * 4 + nn) * 16 + chunk * 2 + ks) << 10) + lb);
    };

    stage(0, 0);
    stage(1, 1);
    loadB(0, bqA);

    #pragma unroll
    for (int c = 0; c < 8; ++c) {
        asm volatile("s_waitcnt vmcnt(10)" ::: "memory");
        __builtin_amdgcn_s_barrier();
        __builtin_amdgcn_sched_barrier(0);
        if (c < 6) stage(c + 2, (c + 2) % 3);
        const int cur = c % 3;
        auto compute = [&](bf16x8 (&bq)[2][4]) {
            #pragma unroll
            for (int ks = 0; ks < 2; ++ks) {
                const int kb = ks * 64 + hi * 16;
                #pragma unroll
                for (int mm = 0; mm < 4; ++mm) {
                    int r = mm * 16 + lo;
                    bf16x8 a = *reinterpret_cast<const bf16x8*>(
                        sA[cur] + r * 128 + (kb ^ ((r & 7) << 4)));
                    #pragma unroll
                    for (int nn = 0; nn < 4; ++nn)
                        acc[mm][nn] = __builtin_amdgcn_mfma_f32_16x16x32_bf16(
                            a, bq[ks][nn], acc[mm][nn], 0, 0, 0);
                }
            }
        };
        if ((c & 1) == 0) { if (c < 7) loadB(c + 1, bqB); compute(bqA); }
        else              { if (c < 7) loadB(c + 1, bqA); compute(bqB); }
    }

    #pragma unroll
    for (int mm = 0; mm < 4; ++mm) {
        #pragma unroll
        for (int nn = 0; nn < 4; ++nn) {
            int col = wcol + nn * 16 + lo;
            float bv2 = S.bias[col];
            #pragma unroll
            for (int r = 0; r < 4; ++r) {
                int grow = brow + mm * 16 + hi * 4 + r;
                if (grow >= n) continue;
                float v = acc[mm][nn][r] + bv2;
                if (EPI == 1) {
                    float rv = (float)S.resid[(size_t)grow * DFEAT + col];
                    ((__bf16*)S.out)[(size_t)grow * DFEAT + col] =
                        (__bf16)(rv + fmaxf(v, 0.f));
                } else {
                    ((float*)S.out)[(size_t)grow * DFEAT + col] = v;
                }
            }
        }
    }
}

// ---------------------------------------------------------------------------
extern "C" void kernel_launch(void* const* d_in, const int* in_sizes, int n_in,
                              void* d_out, int out_size, void* d_ws, size_t ws_size,
                              hipStream_t stream) {
    const float* x_user  = (const float*)d_in[0];
    const float* x_movie = (const float*)d_in[1];
    const int*   src_um  = (const int*)d_in[2];
    const int*   dst_um  = (const int*)d_in[3];
    const float* w_um    = (const float*)d_in[4];
    const int*   src_mu  = (const int*)d_in[5];
    const int*   dst_mu  = (const int*)d_in[6];
    const float* w_mu    = (const float*)d_in[7];
    const float* c1_um_Wl = (const float*)d_in[8];
    const float* c1_um_Wr = (const float*)d_in[9];
    const float* c1_um_b  = (const float*)d_in[10];
    const float* c1_mu_Wl = (const float*)d_in[11];
    const float* c1_mu_Wr = (const float*)d_in[12];
    const float* c1_mu_b  = (const float*)d_in[13];
    const float* c2_um_Wl = (const float*)d_in[14];
    const float* c2_um_Wr = (const float*)d_in[15];
    const float* c2_um_b  = (const float*)d_in[16];
    const float* c2_mu_Wl = (const float*)d_in[17];
    const float* c2_mu_Wr = (const float*)d_in[18];
    const float* c2_mu_b  = (const float*)d_in[19];

    const int NU = in_sizes[0] / DFEAT;
    const int NM = in_sizes[1] / DFEAT;
    const int E_um = in_sizes[2];
    const int E_mu = in_sizes[5];

    char* p = (char*)d_ws;
    auto carve = [&](size_t bytes) { char* r = p; p += (bytes + 255) & ~(size_t)255; return r; };
    int* rowptr_m = (int*)carve((size_t)(NM + 1) * 4);
    int* rowptr_u = (int*)carve((size_t)(NU + 1) * 4);
    int* cursor_m = (int*)carve((size_t)NM * 4);
    int* cursor_u = (int*)carve((size_t)NU * 4);
    int* bsum_m   = (int*)carve(64 * 4);
    int* bsum_u   = (int*)carve(64 * 4);
    __bf16* xu_bf = (__bf16*)carve((size_t)NU * DFEAT * 2);
    __bf16* xm_bf = (__bf16*)carve((size_t)NM * DFEAT * 2);
    __bf16* ru_bf = (__bf16*)carve((size_t)NU * DFEAT * 2);
    __bf16* rm_bf = (__bf16*)carve((size_t)NM * DFEAT * 2);
    __bf16* wt_c1um = (__bf16*)carve(256 * 512 * 2);
    __bf16* wt_c1mu = (__bf16*)carve(256 * 512 * 2);
    __bf16* wt_c2um = (__bf16*)carve(256 * 512 * 2);
    __bf16* wt_c2mu = (__bf16*)carve(256 * 512 * 2);

    // 4B packed records in the dead tail of d_out (consumed before final writes)
    char* dtail = (char*)d_out + (size_t)(NU + NM) * DFEAT * 2;
    unsigned int* rec_m = (unsigned int*)(dtail);
    unsigned int* rec_u = (unsigned int*)(dtail + (size_t)E_um * 4);

    __bf16* mean1_u = (__bf16*)d_out;
    __bf16* mean1_m = (__bf16*)d_out + (size_t)NU * DFEAT;
    float* out_user  = (float*)d_out;
    float* out_movie = (float*)d_out + (size_t)NU * DFEAT;

    // ---- CSR build ----
    size_t msz = ((((size_t)(NM + 1) * 4) + 255) & ~(size_t)255) + (size_t)(NU + 1) * 4;
    (void)hipMemsetAsync(rowptr_m, 0, msz, stream);   // covers rowptr_m + rowptr_u
    hist2_kernel<<<4096, 256, 0, stream>>>(dst_um, E_um, rowptr_m, dst_mu, E_mu, rowptr_u);
    const int nbM = (NM + 1 + 2047) / 2048;
    const int nbU = (NU + 1 + 2047) / 2048;
    scan_block2<<<nbM + nbU, 256, 0, stream>>>(rowptr_m, NM + 1, bsum_m, rowptr_u, NU + 1, bsum_u, nbM);
    scan_sums2<<<1, 128, 0, stream>>>(bsum_m, nbM, bsum_u, nbU);
    scan_add2<<<nbM + nbU, 256, 0, stream>>>(rowptr_m, NM + 1, bsum_m, cursor_m,
                                             rowptr_u, NU + 1, bsum_u, cursor_u, nbM);

    // ---- mega prep: XCD-partitioned fill + nt conversions + nt weights ----
    PrepArgs pa;
    pa.dstA = dst_um; pa.srcA = src_um; pa.wA = w_um; pa.nA = E_um; pa.ndA = NM; pa.curA = cursor_m; pa.recA = rec_m;
    pa.dstB = dst_mu; pa.srcB = src_mu; pa.wB = w_mu; pa.nB = E_mu; pa.ndB = NU; pa.curB = cursor_u; pa.recB = rec_u;
    pa.xu = x_user;  pa.xu_bf = xu_bf; pa.n8u = NU * DFEAT / 8;
    pa.xm = x_movie; pa.xm_bf = xm_bf; pa.n8m = NM * DFEAT / 8;
    pa.Wl[0] = c1_um_Wl; pa.Wr[0] = c1_um_Wr; pa.wout[0] = wt_c1um;
    pa.Wl[1] = c1_mu_Wl; pa.Wr[1] = c1_mu_Wr; pa.wout[1] = wt_c1mu;
    pa.Wl[2] = c2_um_Wl; pa.Wr[2] = c2_um_Wr; pa.wout[2] = wt_c2um;
    pa.Wl[3] = c2_mu_Wl; pa.Wr[3] = c2_mu_Wr; pa.wout[3] = wt_c2mu;
    mega_prep<<<8192, 256, 0, stream>>>(pa);

    const int gaM = (NM + 3) / 4, gaU = (NU + 3) / 4;
    const int gbM = (NM + 63) / 64, gbU = (NU + 63) / 64;

    // ---- layer 1 ----
    agg_dual<<<gaM + gaU, 256, 0, stream>>>(xu_bf, rec_m, rowptr_m, mean1_m, NM, gaM,
                                            xm_bf, rec_u, rowptr_u, mean1_u, NU);
    GemmSide g1m = {mean1_m, xm_bf, wt_c1um, c1_um_b, xm_bf, rm_bf, NM};
    GemmSide g1u = {mean1_u, xu_bf, wt_c1mu, c1_mu_b, xu_bf, ru_bf, NU};
    gemm_dual<1><<<gbM + gbU, 256, 0, stream>>>(g1m, g1u, gbM);

    // ---- layer 2 (means reuse dead x_bf buffers) ----
    __bf16* mean2_m = xm_bf;
    __bf16* mean2_u = xu_bf;
    agg_dual<<<gaM + gaU, 256, 0, stream>>>(ru_bf, rec_m, rowptr_m, mean2_m, NM, gaM,
                                            rm_bf, rec_u, rowptr_u, mean2_u, NU);
    GemmSide g2m = {mean2_m, rm_bf, wt_c2um, c2_um_b, nullptr, out_movie, NM};
    GemmSide g2u = {mean2_u, ru_bf, wt_c2mu, c2_mu_b, nullptr, out_user, NU};
    gemm_dual<0><<<gbM + gbU, 256, 0, stream>>>(g2m, g2u, gbM);
}

// Round 22
// 615.321 us; speedup vs baseline: 3.1051x; 1.0005x over previous
//
#include <hip/hip_runtime.h>
#include <hip/hip_bf16.h>

#define DFEAT 256

typedef __bf16 bf16x8 __attribute__((ext_vector_type(8)));
typedef float  f32x4  __attribute__((ext_vector_type(4)));

// ---------------------------------------------------------------------------
// CSR build: histogram -> hierarchical scan (cursor written in scan_add)
// ---------------------------------------------------------------------------
__global__ void hist2_kernel(const int* __restrict__ dA, int nA, int* __restrict__ PA,
                             const int* __restrict__ dB, int nB, int* __restrict__ PB) {
    int half = gridDim.x >> 1;
    if (blockIdx.x < half) {
        for (int e = blockIdx.x * blockDim.x + threadIdx.x; e < nA; e += half * blockDim.x)
            atomicAdd(&PA[dA[e] + 1], 1);
    } else {
        for (int e = (blockIdx.x - half) * blockDim.x + threadIdx.x; e < nB; e += half * blockDim.x)
            atomicAdd(&PB[dB[e] + 1], 1);
    }
}

__global__ __launch_bounds__(256) void scan_block2(
    int* __restrict__ am, int nm, int* __restrict__ bsm,
    int* __restrict__ au, int nu, int* __restrict__ bsu, int nbM)
{
    __shared__ int wsum[4];
    int* a; int n; int* bsum; int bid;
    if ((int)blockIdx.x < nbM) { a = am; n = nm; bsum = bsm; bid = blockIdx.x; }
    else                       { a = au; n = nu; bsum = bsu; bid = blockIdx.x - nbM; }
    const int tid = threadIdx.x;
    const int lane = tid & 63, wv = tid >> 6;
    const int idx = bid * 2048 + tid * 8;
    int v[8];
    #pragma unroll
    for (int i = 0; i < 8; ++i) v[i] = (idx + i < n) ? a[idx + i] : 0;
    #pragma unroll
    for (int i = 1; i < 8; ++i) v[i] += v[i - 1];
    int tsum = v[7];
    int sc = tsum;
    #pragma unroll
    for (int off = 1; off < 64; off <<= 1) {
        int t = __shfl_up(sc, off);
        if (lane >= off) sc += t;
    }
    if (lane == 63) wsum[wv] = sc;
    __syncthreads();
    int wadd = 0;
    for (int w2 = 0; w2 < wv; ++w2) wadd += wsum[w2];
    int texcl = sc - tsum + wadd;
    #pragma unroll
    for (int i = 0; i < 8; ++i)
        if (idx + i < n) a[idx + i] = v[i] + texcl;
    if (tid == 255) bsum[bid] = sc + wadd;
}

__global__ void scan_sums2(int* __restrict__ bsm, int nbM, int* __restrict__ bsu, int nbU) {
    int wv = threadIdx.x >> 6;
    int lane = threadIdx.x & 63;
    int* bs = wv ? bsu : bsm;
    int nb  = wv ? nbU : nbM;
    int v = (lane < nb) ? bs[lane] : 0;
    #pragma unroll
    for (int off = 1; off < 64; off <<= 1) {
        int t = __shfl_up(v, off);
        if (lane >= off) v += t;
    }
    if (lane < nb) bs[lane] = v;
}

// adds block prefixes AND writes the cursor copy (cursor[d] = rowptr[d])
__global__ __launch_bounds__(256) void scan_add2(
    int* __restrict__ am, int nm, const int* __restrict__ bsm, int* __restrict__ curM,
    int* __restrict__ au, int nu, const int* __restrict__ bsu, int* __restrict__ curU, int nbM)
{
    int* a; int n; const int* bsum; int* cur; int bid;
    if ((int)blockIdx.x < nbM) { a = am; n = nm; bsum = bsm; cur = curM; bid = blockIdx.x; }
    else                       { a = au; n = nu; bsum = bsu; cur = curU; bid = blockIdx.x - nbM; }
    int add = (bid == 0) ? 0 : bsum[bid - 1];
    int idx = bid * 2048 + threadIdx.x * 8;
    #pragma unroll
    for (int i = 0; i < 8; ++i) {
        if (idx + i < n) {
            int v = a[idx + i] + add;
            if (bid > 0) a[idx + i] = v;
            if (idx + i < n - 1) cur[idx + i] = v;
        }
    }
}

// ---------------------------------------------------------------------------
// Mega-prep: [0,4096) XCD-partitioned edge fill (4B packed records) |
// [4096,6144) f32->bf16 | [6144,8192) packed weight transpose.
// All streaming traffic non-temporal; record stores cached.
// ---------------------------------------------------------------------------
struct PrepArgs {
    const int* dstA; const int* srcA; const float* wA; int nA; int ndA;
    int* curA; unsigned int* recA;
    const int* dstB; const int* srcB; const float* wB; int nB; int ndB;
    int* curB; unsigned int* recB;
    const float* xu; __bf16* xu_bf; int n8u;
    const float* xm; __bf16* xm_bf; int n8m;
    const float* Wl[4]; const float* Wr[4]; __bf16* wout[4];
};

__global__ __launch_bounds__(256) void mega_prep(PrepArgs p) {
    const int b = blockIdx.x;
    const int tid = threadIdx.x;
    if (b < 4096) {
        const int* dst; const int* src; const float* w; int n; int ndst; int* cur; unsigned int* rec;
        int within;
        if (b < 2048) { dst = p.dstA; src = p.srcA; w = p.wA; n = p.nA; ndst = p.ndA; cur = p.curA; rec = p.recA; within = b; }
        else          { dst = p.dstB; src = p.srcB; w = p.wB; n = p.nB; ndst = p.ndB; cur = p.curB; rec = p.recB; within = b - 2048; }
        const int r  = within & 7;          // dst-range == XCD group (blockIdx%8)
        const int lb = within >> 3;         // 0..255 within range-group
        const int rsz = (ndst + 7) >> 3;
        const int d0 = r * rsz;
        const int d1 = (d0 + rsz < ndst) ? d0 + rsz : ndst;
        for (int e = lb * 256 + tid; e < n; e += 256 * 256) {
            int d = __builtin_nontemporal_load(dst + e);   // nt: don't pollute L2
            if (d >= d0 && d < d1) {
                int pos = atomicAdd(&cur[d], 1);
                float wv = __builtin_nontemporal_load(w + e);
                unsigned int sv = (unsigned int)__builtin_nontemporal_load(src + e);
                unsigned int wq = (unsigned int)fminf(rintf(wv * 32768.0f), 32767.0f);
                rec[pos] = (sv << 15) | wq;
            }
        }
    } else if (b < 6144) {
        int total = p.n8u + p.n8m;
        for (int i = (b - 4096) * 256 + tid; i < total; i += 2048 * 256) {
            const float* in; __bf16* out; int j;
            if (i < p.n8u) { in = p.xu; out = p.xu_bf; j = i; }
            else           { in = p.xm; out = p.xm_bf; j = i - p.n8u; }
            const f32x4* p4 = reinterpret_cast<const f32x4*>(in + (size_t)j * 8);
            f32x4 x = __builtin_nontemporal_load(p4);
            f32x4 y = __builtin_nontemporal_load(p4 + 1);
            bf16x8 v;
            v[0] = (__bf16)x[0]; v[1] = (__bf16)x[1]; v[2] = (__bf16)x[2]; v[3] = (__bf16)x[3];
            v[4] = (__bf16)y[0]; v[5] = (__bf16)y[1]; v[6] = (__bf16)y[2]; v[7] = (__bf16)y[3];
            __builtin_nontemporal_store(v, reinterpret_cast<bf16x8*>(out + (size_t)j * 8));
        }
    } else {
        // packed fragment-major weights: frag f = ncg*16+kc; lane l bytes f*1024+l*16
        int t = (b - 6144) * 256 + tid;          // 0 .. 524287
        int set = t >> 17;
        int e2  = t & 131071;
        int f = e2 >> 9;
        int e = e2 & 511;
        int l = e >> 3;
        int j = e & 7;
        int ncg = f >> 4;
        int kc  = f & 15;
        int col = ncg * 16 + (l & 15);
        int k   = kc * 32 + (l >> 4) * 8 + j;
        const float* wp = (k < 256) ? &p.Wl[set][(size_t)k * 256 + col]
                                    : &p.Wr[set][(size_t)(k - 256) * 256 + col];
        float v = __builtin_nontemporal_load(wp);
        __builtin_nontemporal_store((__bf16)v, &p.wout[set][e2]);
    }
}

// ---------------------------------------------------------------------------
// Dual aggregation: one wave per dst row. Per-lane decode hoisted out of the
// step loop (weight float + pre-scaled byte offset, once per 64-edge chunk;
// OOB lanes rl=0 -> weight 0, offset 0). Per step: 4 UNIFORM-index readlanes
// + 2 per-lane selects (readlane requires wave-uniform lane index — folding
// the divergent `half` into the index was R20's correctness bug).
// ---------------------------------------------------------------------------
__global__ __launch_bounds__(256) void agg_dual(
    const __bf16* __restrict__ xA, const unsigned int* __restrict__ recA,
    const int* __restrict__ rpA, __bf16* __restrict__ meanA, int ndA, int nbA,
    const __bf16* __restrict__ xB, const unsigned int* __restrict__ recB,
    const int* __restrict__ rpB, __bf16* __restrict__ meanB, int ndB)
{
    const __bf16* xsrc; const unsigned int* rec; const int* rowptr; __bf16* mean; int ndst; int lb;
    if ((int)blockIdx.x < nbA) { xsrc = xA; rec = recA; rowptr = rpA; mean = meanA; ndst = ndA; lb = blockIdx.x; }
    else                       { xsrc = xB; rec = recB; rowptr = rpB; mean = meanB; ndst = ndB; lb = blockIdx.x - nbA; }
    int wid  = lb * 4 + (threadIdx.x >> 6);
    int lane = threadIdx.x & 63;
    if (wid >= ndst) return;
    int beg = rowptr[wid], end = rowptr[wid + 1];
    const int half = lane >> 5, hl = lane & 31;
    const char* xcol = reinterpret_cast<const char*>(xsrc + hl * 8);
    const float wscale = 1.0f / 32768.0f;
    float acc[8];
    #pragma unroll
    for (int i = 0; i < 8; ++i) acc[i] = 0.f;

    int j0 = beg;
    while (j0 < end) {
        int m = end - j0; if (m > 64) m = 64;
        unsigned int rl = (lane < m) ? rec[j0 + lane] : 0u;
        float wf  = (float)(rl & 32767u) * wscale;   // per-lane decode, once
        int  boff = (int)(rl >> 15) << 9;            // byte offset = src*512
        int  wfi  = __float_as_int(wf);
        for (int t = 0; t < m; t += 16) {
            bf16x8 v[8]; float wt[8];
            #pragma unroll
            for (int u = 0; u < 8; ++u) {
                int tt = t + u * 2;                  // uniform; tt+1 <= 63
                int o0 = __builtin_amdgcn_readlane(boff, tt);
                int o1 = __builtin_amdgcn_readlane(boff, tt + 1);
                int w0 = __builtin_amdgcn_readlane(wfi, tt);
                int w1 = __builtin_amdgcn_readlane(wfi, tt + 1);
                int eo = half ? o1 : o0;
                wt[u] = __int_as_float(half ? w1 : w0);
                v[u] = *reinterpret_cast<const bf16x8*>(xcol + eo);
            }
            #pragma unroll
            for (int u = 0; u < 8; ++u)
                #pragma unroll
                for (int i = 0; i < 8; ++i) acc[i] += wt[u] * (float)v[u][i];
        }
        j0 += m;
    }

    #pragma unroll
    for (int i = 0; i < 8; ++i) acc[i] += __shfl_xor(acc[i], 32);
    float inv = (end > beg) ? 1.0f / (float)(end - beg) : 0.0f;
    if (half == 0) {
        bf16x8 o;
        #pragma unroll
        for (int i = 0; i < 8; ++i) o[i] = (__bf16)(acc[i] * inv);
        *reinterpret_cast<bf16x8*>(mean + (size_t)wid * DFEAT + hl * 8) = o;
    }
}

// ---------------------------------------------------------------------------
// Dual MFMA GEMM, 2-deep pipeline (R10 structure): out = epi(A@Wl + B@Wr + b)
// ---------------------------------------------------------------------------
struct GemmSide {
    const __bf16* A; const __bf16* B; const __bf16* W;
    const float* bias; const __bf16* resid; void* out; int n;
};

template<int EPI>
__global__ __launch_bounds__(256) void gemm_dual(GemmSide s0, GemmSide s1, int nb0) {
    __shared__ char sA[3][64 * 128];      // 3 x 8 KB

    const GemmSide& S = ((int)blockIdx.x < nb0) ? s0 : s1;
    const int lblk = ((int)blockIdx.x < nb0) ? blockIdx.x : blockIdx.x - nb0;
    const __bf16* __restrict__ Amat = S.A;
    const __bf16* __restrict__ Bmat = S.B;
    const char* Wb = reinterpret_cast<const char*>(S.W);
    const int n = S.n;

    const int tid  = threadIdx.x;
    const int lane = tid & 63;
    const int wv   = tid >> 6;
    const int lo   = lane & 15;
    const int hi   = lane >> 4;
    const int brow = lblk * 64;
    const int wcol = wv * 64;
    const int nm1  = n - 1;

    f32x4 acc[4][4];
    #pragma unroll
    for (int i = 0; i < 4; ++i)
        #pragma unroll
        for (int j = 0; j < 4; ++j) acc[i][j] = (f32x4){0.f, 0.f, 0.f, 0.f};

    auto stage = [&](int chunk, int buf) {
        const __bf16* mat = (chunk < 4) ? Amat : Bmat;
        const int kbyte = (chunk & 3) * 128;
        #pragma unroll
        for (int q = 0; q < 2; ++q) {
            int s = q * 256 + tid;
            int r = s >> 3, sub = s & 7;
            int grow = brow + r; if (grow > nm1) grow = nm1;
            int srcoff = (sub * 16) ^ ((r & 7) << 4);
            const char* g = reinterpret_cast<const char*>(mat) + (size_t)grow * 512 + kbyte + srcoff;
            __builtin_amdgcn_global_load_lds(
                (const __attribute__((address_space(1))) void*)g,
                (__attribute__((address_space(3))) void*)(sA[buf] + s * 16), 16, 0, 0);
        }
    };

    const int lb = lane * 16;
    bf16x8 bqA[2][4], bqB[2][4];
    auto loadB = [&](int chunk, bf16x8 (&dst)[2][4]) {
        #pragma unroll
        for (int ks = 0; ks < 2; ++ks)
            #pragma unroll
            for (int nn = 0; nn < 4; ++nn)
                dst[ks][nn] = *reinterpret_cast<const bf16x8*>(
                    Wb + (size_t)(((wv * 4 + nn) * 16 + chunk * 2 + ks) << 10) + lb);
    };

    stage(0, 0);
    stage(1, 1);
    loadB(0, bqA);

    #pragma unroll
    for (int c = 0; c < 8; ++c) {
        asm volatile("s_waitcnt vmcnt(10)" ::: "memory");
        __builtin_amdgcn_s_barrier();
        __builtin_amdgcn_sched_barrier(0);
        if (c < 6) stage(c + 2, (c + 2) % 3);
        const int cur = c % 3;
        auto compute = [&](bf16x8 (&bq)[2][4]) {
            #pragma unroll
            for (int ks = 0; ks < 2; ++ks) {
                const int kb = ks * 64 + hi * 16;
                #pragma unroll
                for (int mm = 0; mm < 4; ++mm) {
                    int r = mm * 16 + lo;
                    bf16x8 a = *reinterpret_cast<const bf16x8*>(
                        sA[cur] + r * 128 + (kb ^ ((r & 7) << 4)));
                    #pragma unroll
                    for (int nn = 0; nn < 4; ++nn)
                        acc[mm][nn] = __builtin_amdgcn_mfma_f32_16x16x32_bf16(
                            a, bq[ks][nn], acc[mm][nn], 0, 0, 0);
                }
            }
        };
        if ((c & 1) == 0) { if (c < 7) loadB(c + 1, bqB); compute(bqA); }
        else              { if (c < 7) loadB(c + 1, bqA); compute(bqB); }
    }

    #pragma unroll
    for (int mm = 0; mm < 4; ++mm) {
        #pragma unroll
        for (int nn = 0; nn < 4; ++nn) {
            int col = wcol + nn * 16 + lo;
            float bv2 = S.bias[col];
            #pragma unroll
            for (int r = 0; r < 4; ++r) {
                int grow = brow + mm * 16 + hi * 4 + r;
                if (grow >= n) continue;
                float v = acc[mm][nn][r] + bv2;
                if (EPI == 1) {
                    float rv = (float)S.resid[(size_t)grow * DFEAT + col];
                    ((__bf16*)S.out)[(size_t)grow * DFEAT + col] =
                        (__bf16)(rv + fmaxf(v, 0.f));
                } else {
                    ((float*)S.out)[(size_t)grow * DFEAT + col] = v;
                }
            }
        }
    }
}

// ---------------------------------------------------------------------------
extern "C" void kernel_launch(void* const* d_in, const int* in_sizes, int n_in,
                              void* d_out, int out_size, void* d_ws, size_t ws_size,
                              hipStream_t stream) {
    const float* x_user  = (const float*)d_in[0];
    const float* x_movie = (const float*)d_in[1];
    const int*   src_um  = (const int*)d_in[2];
    const int*   dst_um  = (const int*)d_in[3];
    const float* w_um    = (const float*)d_in[4];
    const int*   src_mu  = (const int*)d_in[5];
    const int*   dst_mu  = (const int*)d_in[6];
    const float* w_mu    = (const float*)d_in[7];
    const float* c1_um_Wl = (const float*)d_in[8];
    const float* c1_um_Wr = (const float*)d_in[9];
    const float* c1_um_b  = (const float*)d_in[10];
    const float* c1_mu_Wl = (const float*)d_in[11];
    const float* c1_mu_Wr = (const float*)d_in[12];
    const float* c1_mu_b  = (const float*)d_in[13];
    const float* c2_um_Wl = (const float*)d_in[14];
    const float* c2_um_Wr = (const float*)d_in[15];
    const float* c2_um_b  = (const float*)d_in[16];
    const float* c2_mu_Wl = (const float*)d_in[17];
    const float* c2_mu_Wr = (const float*)d_in[18];
    const float* c2_mu_b  = (const float*)d_in[19];

    const int NU = in_sizes[0] / DFEAT;
    const int NM = in_sizes[1] / DFEAT;
    const int E_um = in_sizes[2];
    const int E_mu = in_sizes[5];

    char* p = (char*)d_ws;
    auto carve = [&](size_t bytes) { char* r = p; p += (bytes + 255) & ~(size_t)255; return r; };
    int* rowptr_m = (int*)carve((size_t)(NM + 1) * 4);
    int* rowptr_u = (int*)carve((size_t)(NU + 1) * 4);
    int* cursor_m = (int*)carve((size_t)NM * 4);
    int* cursor_u = (int*)carve((size_t)NU * 4);
    int* bsum_m   = (int*)carve(64 * 4);
    int* bsum_u   = (int*)carve(64 * 4);
    __bf16* xu_bf = (__bf16*)carve((size_t)NU * DFEAT * 2);
    __bf16* xm_bf = (__bf16*)carve((size_t)NM * DFEAT * 2);
    __bf16* ru_bf = (__bf16*)carve((size_t)NU * DFEAT * 2);
    __bf16* rm_bf = (__bf16*)carve((size_t)NM * DFEAT * 2);
    __bf16* wt_c1um = (__bf16*)carve(256 * 512 * 2);
    __bf16* wt_c1mu = (__bf16*)carve(256 * 512 * 2);
    __bf16* wt_c2um = (__bf16*)carve(256 * 512 * 2);
    __bf16* wt_c2mu = (__bf16*)carve(256 * 512 * 2);

    // 4B packed records in the dead tail of d_out (consumed before final writes)
    char* dtail = (char*)d_out + (size_t)(NU + NM) * DFEAT * 2;
    unsigned int* rec_m = (unsigned int*)(dtail);
    unsigned int* rec_u = (unsigned int*)(dtail + (size_t)E_um * 4);

    __bf16* mean1_u = (__bf16*)d_out;
    __bf16* mean1_m = (__bf16*)d_out + (size_t)NU * DFEAT;
    float* out_user  = (float*)d_out;
    float* out_movie = (float*)d_out + (size_t)NU * DFEAT;

    // ---- CSR build ----
    size_t msz = ((((size_t)(NM + 1) * 4) + 255) & ~(size_t)255) + (size_t)(NU + 1) * 4;
    (void)hipMemsetAsync(rowptr_m, 0, msz, stream);   // covers rowptr_m + rowptr_u
    hist2_kernel<<<4096, 256, 0, stream>>>(dst_um, E_um, rowptr_m, dst_mu, E_mu, rowptr_u);
    const int nbM = (NM + 1 + 2047) / 2048;
    const int nbU = (NU + 1 + 2047) / 2048;
    scan_block2<<<nbM + nbU, 256, 0, stream>>>(rowptr_m, NM + 1, bsum_m, rowptr_u, NU + 1, bsum_u, nbM);
    scan_sums2<<<1, 128, 0, stream>>>(bsum_m, nbM, bsum_u, nbU);
    scan_add2<<<nbM + nbU, 256, 0, stream>>>(rowptr_m, NM + 1, bsum_m, cursor_m,
                                             rowptr_u, NU + 1, bsum_u, cursor_u, nbM);

    // ---- mega prep: XCD-partitioned fill + nt conversions + nt weights ----
    PrepArgs pa;
    pa.dstA = dst_um; pa.srcA = src_um; pa.wA = w_um; pa.nA = E_um; pa.ndA = NM; pa.curA = cursor_m; pa.recA = rec_m;
    pa.dstB = dst_mu; pa.srcB = src_mu; pa.wB = w_mu; pa.nB = E_mu; pa.ndB = NU; pa.curB = cursor_u; pa.recB = rec_u;
    pa.xu = x_user;  pa.xu_bf = xu_bf; pa.n8u = NU * DFEAT / 8;
    pa.xm = x_movie; pa.xm_bf = xm_bf; pa.n8m = NM * DFEAT / 8;
    pa.Wl[0] = c1_um_Wl; pa.Wr[0] = c1_um_Wr; pa.wout[0] = wt_c1um;
    pa.Wl[1] = c1_mu_Wl; pa.Wr[1] = c1_mu_Wr; pa.wout[1] = wt_c1mu;
    pa.Wl[2] = c2_um_Wl; pa.Wr[2] = c2_um_Wr; pa.wout[2] = wt_c2um;
    pa.Wl[3] = c2_mu_Wl; pa.Wr[3] = c2_mu_Wr; pa.wout[3] = wt_c2mu;
    mega_prep<<<8192, 256, 0, stream>>>(pa);

    const int gaM = (NM + 3) / 4, gaU = (NU + 3) / 4;
    const int gbM = (NM + 63) / 64, gbU = (NU + 63) / 64;

    // ---- layer 1 ----
    agg_dual<<<gaM + gaU, 256, 0, stream>>>(xu_bf, rec_m, rowptr_m, mean1_m, NM, gaM,
                                            xm_bf, rec_u, rowptr_u, mean1_u, NU);
    GemmSide g1m = {mean1_m, xm_bf, wt_c1um, c1_um_b, xm_bf, rm_bf, NM};
    GemmSide g1u = {mean1_u, xu_bf, wt_c1mu, c1_mu_b, xu_bf, ru_bf, NU};
    gemm_dual<1><<<gbM + gbU, 256, 0, stream>>>(g1m, g1u, gbM);

    // ---- layer 2 (means reuse dead x_bf buffers) ----
    __bf16* mean2_m = xm_bf;
    __bf16* mean2_u = xu_bf;
    agg_dual<<<gaM + gaU, 256, 0, stream>>>(ru_bf, rec_m, rowptr_m, mean2_m, NM, gaM,
                                            rm_bf, rec_u, rowptr_u, mean2_u, NU);
    GemmSide g2m = {mean2_m, rm_bf, wt_c2um, c2_um_b, nullptr, out_movie, NM};
    GemmSide g2u = {mean2_u, ru_bf, wt_c2mu, c2_mu_b, nullptr, out_user, NU};
    gemm_dual<0><<<gbM + gbU, 256, 0, stream>>>(g2m, g2u, gbM);
}